// Round 2
// baseline (28387.143 us; speedup 1.0000x reference)
//
#include <hip/hip_runtime.h>
#include <math.h>

#define NN 50000
#define NE 800000
#define FIN 197
#define H 256
#define HEADS 8
#define HD 32
#define LAYERS 5
#define FF 1024
#define INV_SCALE 0.17677669529663687f   // 1/sqrt(32)

__device__ __forceinline__ float gelu_f(float x) {
    return 0.5f * x * (1.0f + erff(x * 0.7071067811865476f));
}

// monotone float<->uint key for atomicMax-based segment max
__device__ __forceinline__ unsigned fkey(float f) {
    unsigned b = __float_as_uint(f);
    return (b & 0x80000000u) ? ~b : (b | 0x80000000u);
}

// C[r, c] = act(A[r,:] @ B[:,c] + bias[c]) + res[r,c]
// A: n x K (stride lda), B: K x M' slice (stride ldb), C: n x M (stride ldc)
// M must be a multiple of 64; grid.x = M/64, grid.y = ceil(n/64)
__global__ __launch_bounds__(256) void gemm_kernel(
    const float* __restrict__ A, int lda,
    const float* __restrict__ B, int ldb,
    const float* __restrict__ bias, const float* __restrict__ res, int ldr,
    float* __restrict__ C, int ldc, int n, int K, int M, int act)
{
    __shared__ float As[16][65];
    __shared__ float Bs[16][64];
    int tid = threadIdx.x;
    int brow = blockIdx.y * 64;
    int bcol = blockIdx.x * 64;
    int tr = tid >> 4, tc = tid & 15;
    float acc[4][4] = {};
    for (int k0 = 0; k0 < K; k0 += 16) {
        #pragma unroll
        for (int i = 0; i < 4; ++i) {
            int idx = tid + i * 256;        // 64x16 A tile
            int r = idx >> 4, c = idx & 15;
            int gr = brow + r, gc = k0 + c;
            As[c][r] = (gr < n && gc < K) ? A[(long)gr * lda + gc] : 0.f;
        }
        #pragma unroll
        for (int i = 0; i < 4; ++i) {
            int idx = tid + i * 256;        // 16x64 B tile
            int r = idx >> 6, c = idx & 63;
            int gr = k0 + r;
            Bs[r][c] = (gr < K) ? B[(long)gr * ldb + bcol + c] : 0.f;
        }
        __syncthreads();
        #pragma unroll
        for (int kk = 0; kk < 16; ++kk) {
            float a0 = As[kk][tr * 4 + 0], a1 = As[kk][tr * 4 + 1];
            float a2 = As[kk][tr * 4 + 2], a3 = As[kk][tr * 4 + 3];
            float b0 = Bs[kk][tc * 4 + 0], b1 = Bs[kk][tc * 4 + 1];
            float b2 = Bs[kk][tc * 4 + 2], b3 = Bs[kk][tc * 4 + 3];
            acc[0][0] += a0 * b0; acc[0][1] += a0 * b1; acc[0][2] += a0 * b2; acc[0][3] += a0 * b3;
            acc[1][0] += a1 * b0; acc[1][1] += a1 * b1; acc[1][2] += a1 * b2; acc[1][3] += a1 * b3;
            acc[2][0] += a2 * b0; acc[2][1] += a2 * b1; acc[2][2] += a2 * b2; acc[2][3] += a2 * b3;
            acc[3][0] += a3 * b0; acc[3][1] += a3 * b1; acc[3][2] += a3 * b2; acc[3][3] += a3 * b3;
        }
        __syncthreads();
    }
    #pragma unroll
    for (int i = 0; i < 4; ++i) {
        int gr = brow + tr * 4 + i;
        if (gr >= n) continue;
        #pragma unroll
        for (int j = 0; j < 4; ++j) {
            int gc = bcol + tc * 4 + j;
            float v = acc[i][j];
            if (bias) v += bias[gc];
            if (act) v = gelu_f(v);
            if (res) v += res[(long)gr * ldr + gc];
            C[(long)gr * ldc + gc] = v;
        }
    }
}

// LayerNorm over rows of width 256; one wave per row, 4 rows/block.
__global__ __launch_bounds__(256) void ln256_kernel(
    const float* __restrict__ a, const float* __restrict__ res,
    const float* __restrict__ g, const float* __restrict__ bta,
    float* __restrict__ out, int n, int post_gelu)
{
    int row = blockIdx.x * 4 + (threadIdx.x >> 6);
    if (row >= n) return;
    int lane = threadIdx.x & 63;
    float4 v = *(const float4*)(a + (long)row * H + lane * 4);
    if (res) {
        float4 r = *(const float4*)(res + (long)row * H + lane * 4);
        v.x += r.x; v.y += r.y; v.z += r.z; v.w += r.w;
    }
    float s = v.x + v.y + v.z + v.w;
    #pragma unroll
    for (int off = 1; off < 64; off <<= 1) s += __shfl_xor(s, off);
    float mean = s * (1.0f / H);
    float dx = v.x - mean, dy = v.y - mean, dz = v.z - mean, dw = v.w - mean;
    float qs = dx * dx + dy * dy + dz * dz + dw * dw;
    #pragma unroll
    for (int off = 1; off < 64; off <<= 1) qs += __shfl_xor(qs, off);
    float rstd = rsqrtf(qs * (1.0f / H) + 1e-5f);
    float4 gg = *(const float4*)(g + lane * 4);
    float4 bb = *(const float4*)(bta + lane * 4);
    float4 o;
    o.x = dx * rstd * gg.x + bb.x;
    o.y = dy * rstd * gg.y + bb.y;
    o.z = dz * rstd * gg.z + bb.z;
    o.w = dw * rstd * gg.w + bb.w;
    if (post_gelu) { o.x = gelu_f(o.x); o.y = gelu_f(o.y); o.z = gelu_f(o.z); o.w = gelu_f(o.w); }
    *(float4*)(out + (long)row * H + lane * 4) = o;
}

// per head-group (2 heads): score + atomic segment-max
__global__ __launch_bounds__(256) void score_kernel(
    const float* __restrict__ qg, const float* __restrict__ kg,
    const int* __restrict__ src, const int* __restrict__ dst,
    const float* __restrict__ ea, const float* __restrict__ We,
    const float* __restrict__ be, int g,
    float* __restrict__ score, unsigned* __restrict__ mxkey)
{
    int i = blockIdx.x * 256 + threadIdx.x;
    if (i >= NE * 2) return;
    int e = i >> 1, hh = i & 1;
    int hg = g * 2 + hh;
    int s = src[e], d = dst[e];
    const float4* qp = (const float4*)(qg + (long)d * 64 + hh * 32);
    const float4* kp = (const float4*)(kg + (long)s * 64 + hh * 32);
    float acc = 0.f;
    #pragma unroll
    for (int j = 0; j < 8; ++j) {
        float4 a = qp[j], b = kp[j];
        acc += a.x * b.x + a.y * b.y + a.z * b.z + a.w * b.w;
    }
    float sc = acc * INV_SCALE + ea[e * 2 + 0] * We[hg] + ea[e * 2 + 1] * We[8 + hg] + be[hg];
    score[i] = sc;
    atomicMax(&mxkey[d * 2 + hh], fkey(sc));
}

__global__ __launch_bounds__(256) void ex_kernel(
    float* __restrict__ score, const unsigned* __restrict__ mxkey,
    const int* __restrict__ dst, float* __restrict__ denom)
{
    int i = blockIdx.x * 256 + threadIdx.x;
    if (i >= NE * 2) return;
    int e = i >> 1, hh = i & 1;
    int d = dst[e];
    unsigned k = mxkey[d * 2 + hh];
    float mx = __uint_as_float((k & 0x80000000u) ? (k & 0x7FFFFFFFu) : ~k);
    float ev = expf(score[i] - mx);
    score[i] = ev;
    atomicAdd(&denom[d * 2 + hh], ev);
}

// agg[dst, g*64 + c] += (ex/denom) * vg[src, c] ; thread per (edge, float4)
__global__ __launch_bounds__(256) void scatter_kernel(
    const float* __restrict__ ex, const float* __restrict__ denom,
    const float* __restrict__ vg, const int* __restrict__ src,
    const int* __restrict__ dst, int g, float* __restrict__ agg)
{
    long i = (long)blockIdx.x * 256 + threadIdx.x;
    if (i >= (long)NE * 16) return;
    int e = (int)(i >> 4);
    int c4 = (int)(i & 15);
    int hh = c4 >> 3;
    int s = src[e], d = dst[e];
    float w = ex[(long)e * 2 + hh] / (denom[(long)d * 2 + hh] + 1e-16f);
    float4 vv = *(const float4*)(vg + (long)s * 64 + c4 * 4);
    float* ap = agg + (long)d * H + g * 64 + c4 * 4;
    atomicAdd(ap + 0, w * vv.x);
    atomicAdd(ap + 1, w * vv.y);
    atomicAdd(ap + 2, w * vv.z);
    atomicAdd(ap + 3, w * vv.w);
}

// logits = t1 @ W(128x2) + b ; probs = softmax. out = [logits | probs]
__global__ __launch_bounds__(256) void cls_kernel(
    const float* __restrict__ t1, const float* __restrict__ W,
    const float* __restrict__ b, float* __restrict__ out)
{
    int i = blockIdx.x * 256 + threadIdx.x;
    if (i >= NN) return;
    const float* tp = t1 + (long)i * 128;
    float a0 = 0.f, a1 = 0.f;
    #pragma unroll
    for (int j = 0; j < 128; j += 4) {
        float4 t = *(const float4*)(tp + j);
        a0 += t.x * W[(j + 0) * 2] + t.y * W[(j + 1) * 2] + t.z * W[(j + 2) * 2] + t.w * W[(j + 3) * 2];
        a1 += t.x * W[(j + 0) * 2 + 1] + t.y * W[(j + 1) * 2 + 1] + t.z * W[(j + 2) * 2 + 1] + t.w * W[(j + 3) * 2 + 1];
    }
    float l0 = a0 + b[0], l1 = a1 + b[1];
    out[(long)i * 2 + 0] = l0;
    out[(long)i * 2 + 1] = l1;
    float m = fmaxf(l0, l1);
    float p0 = expf(l0 - m), p1 = expf(l1 - m);
    float sden = p0 + p1;
    out[2L * NN + (long)i * 2 + 0] = p0 / sden;
    out[2L * NN + (long)i * 2 + 1] = p1 / sden;
}

extern "C" void kernel_launch(void* const* d_in, const int* in_sizes, int n_in,
                              void* d_out, int out_size, void* d_ws, size_t ws_size,
                              hipStream_t stream) {
    const float* x      = (const float*)d_in[0];
    const int*   ei     = (const int*)d_in[1];
    const float* ea     = (const float*)d_in[2];
    const float* in_W   = (const float*)d_in[3];
    const float* in_b   = (const float*)d_in[4];
    const float* in_g   = (const float*)d_in[5];
    const float* in_bb  = (const float*)d_in[6];
    const float* Wq     = (const float*)d_in[7];
    const float* Wk     = (const float*)d_in[8];
    const float* Wv     = (const float*)d_in[9];
    const float* We     = (const float*)d_in[10];
    const float* be     = (const float*)d_in[11];
    const float* Wo     = (const float*)d_in[12];
    const float* bo     = (const float*)d_in[13];
    const float* ln1_g  = (const float*)d_in[14];
    const float* ln1_b  = (const float*)d_in[15];
    const float* ln2_g  = (const float*)d_in[16];
    const float* ln2_b  = (const float*)d_in[17];
    const float* f1_W   = (const float*)d_in[18];
    const float* f1_b   = (const float*)d_in[19];
    const float* f2_W   = (const float*)d_in[20];
    const float* f2_b   = (const float*)d_in[21];
    const float* cls1_W = (const float*)d_in[22];
    const float* cls1_b = (const float*)d_in[23];
    const float* cls2_W = (const float*)d_in[24];
    const float* cls2_b = (const float*)d_in[25];
    float* out = (float*)d_out;

    const int* src = ei;
    const int* dst = ei + NE;

    // workspace layout (floats). Peak ~199 MB.
    float* B0 = (float*)d_ws;                 // h      : NN*256
    float* B1 = B0 + (long)NN * H;            // hn/outp: NN*256
    float* B2 = B1 + (long)NN * H;            // agg/out: NN*256
    float* P  = B2 + (long)NN * H;            // pool   : 11.4M floats
    float* qg = P;                            // NN*64
    float* kg = qg + (long)NN * 64;           // NN*64
    float* vg = kg + (long)NN * 64;           // NN*64
    float* score = vg + (long)NN * 64;        // NE*2
    unsigned* mxkey = (unsigned*)(score + (long)NE * 2);  // NN*2
    float* denom = (float*)(mxkey + (long)NN * 2);        // NN*2
    // FFN chunk buffer reuses P (10000*1024 = 10.24M <= 11.4M)

    dim3 blk(256);
    const int ln_grid = (NN + 3) / 4;
    const int eh_grid = (NE * 2 + 255) / 256;
    const int sc_grid = (int)(((long)NE * 16 + 255) / 256);

    // input projection: B1 = x@in_W + in_b ; B0 = gelu(LN(B1))
    {
        dim3 g(H / 64, (NN + 63) / 64);
        gemm_kernel<<<g, blk, 0, stream>>>(x, FIN, in_W, H, in_b, nullptr, 0, B1, H, NN, FIN, H, 0);
        ln256_kernel<<<ln_grid, blk, 0, stream>>>(B1, nullptr, in_g, in_bb, B0, NN, 1);
    }

    for (int l = 0; l < LAYERS; ++l) {
        const float* wq = Wq + (long)l * H * H;
        const float* wk = Wk + (long)l * H * H;
        const float* wv = Wv + (long)l * H * H;
        const float* we = We + (long)l * 2 * HEADS;
        const float* bel = be + (long)l * HEADS;
        const float* wo = Wo + (long)l * H * H;
        const float* bol = bo + (long)l * H;
        const float* g1 = ln1_g + (long)l * H;
        const float* b1 = ln1_b + (long)l * H;
        const float* g2 = ln2_g + (long)l * H;
        const float* b2 = ln2_b + (long)l * H;
        const float* w1 = f1_W + (long)l * H * FF;
        const float* bf1 = f1_b + (long)l * FF;
        const float* w2 = f2_W + (long)l * FF * H;
        const float* bf2 = f2_b + (long)l * H;

        // hn = LN(h)
        ln256_kernel<<<ln_grid, blk, 0, stream>>>(B0, nullptr, g1, b1, B1, NN, 0);
        hipMemsetAsync(B2, 0, (size_t)NN * H * 4, stream);   // agg = 0

        dim3 g64(1, (NN + 63) / 64);
        for (int g = 0; g < 4; ++g) {
            // q/k/v column slices (2 heads = 64 cols)
            gemm_kernel<<<g64, blk, 0, stream>>>(B1, H, wq + g * 64, H, nullptr, nullptr, 0, qg, 64, NN, H, 64, 0);
            gemm_kernel<<<g64, blk, 0, stream>>>(B1, H, wk + g * 64, H, nullptr, nullptr, 0, kg, 64, NN, H, 64, 0);
            gemm_kernel<<<g64, blk, 0, stream>>>(B1, H, wv + g * 64, H, nullptr, nullptr, 0, vg, 64, NN, H, 64, 0);
            hipMemsetAsync(mxkey, 0, (size_t)NN * 2 * 4, stream);
            hipMemsetAsync(denom, 0, (size_t)NN * 2 * 4, stream);
            score_kernel<<<eh_grid, blk, 0, stream>>>(qg, kg, src, dst, ea, we, bel, g, score, mxkey);
            ex_kernel<<<eh_grid, blk, 0, stream>>>(score, mxkey, dst, denom);
            scatter_kernel<<<sc_grid, blk, 0, stream>>>(score, denom, vg, src, dst, g, B2);
        }

        // B1 = agg @ Wo + bo ; B2 = LN(B1 + h)
        dim3 gh(H / 64, (NN + 63) / 64);
        gemm_kernel<<<gh, blk, 0, stream>>>(B2, H, wo, H, bol, nullptr, 0, B1, H, NN, H, H, 0);
        ln256_kernel<<<ln_grid, blk, 0, stream>>>(B1, B0, g2, b2, B2, NN, 0);

        // FFN row-chunked: P = gelu(out@W1+b1) (R x 1024); h = P@W2 + b2 + out
        const int R = 10000;
        for (int r0 = 0; r0 < NN; r0 += R) {
            int nr = (NN - r0 < R) ? (NN - r0) : R;
            dim3 gf(FF / 64, (nr + 63) / 64);
            gemm_kernel<<<gf, blk, 0, stream>>>(B2 + (long)r0 * H, H, w1, FF, bf1, nullptr, 0, P, FF, nr, H, FF, 1);
            dim3 gb(H / 64, (nr + 63) / 64);
            gemm_kernel<<<gb, blk, 0, stream>>>(P, FF, w2, H, bf2, B2 + (long)r0 * H, H, B0 + (long)r0 * H, H, nr, FF, H, 0);
        }
    }

    // classifier: B1 = gelu(h @ cls1_W + cls1_b) (NN x 128); then 128->2 + softmax
    {
        dim3 g(128 / 64, (NN + 63) / 64);
        gemm_kernel<<<g, blk, 0, stream>>>(B0, H, cls1_W, 128, cls1_b, nullptr, 0, B1, 128, NN, H, 128, 1);
        cls_kernel<<<(NN + 255) / 256, blk, 0, stream>>>(B1, cls2_W, cls2_b, out);
    }
}

// Round 4
// 18092.371 us; speedup vs baseline: 1.5690x; 1.5690x over previous
//
#include <hip/hip_runtime.h>
#include <math.h>

#define NN 50000
#define NE 800000
#define FIN 197
#define H 256
#define HEADS 8
#define HD 32
#define LAYERS 5
#define FF 1024
#define INV_SCALE 0.17677669529663687f   // 1/sqrt(32)

typedef __attribute__((ext_vector_type(8))) short short8;
typedef __attribute__((ext_vector_type(4))) float f32x4;
typedef unsigned short ushort;

__device__ __forceinline__ float gelu_f(float x) {
    return 0.5f * x * (1.0f + erff(x * 0.7071067811865476f));
}
__device__ __forceinline__ ushort f2b(float f) {        // fp32 -> bf16 RNE
    unsigned u = __float_as_uint(f);
    u += 0x7fffu + ((u >> 16) & 1u);
    return (ushort)(u >> 16);
}
__device__ __forceinline__ unsigned fkey(float f) {     // monotone key for atomicMax
    unsigned b = __float_as_uint(f);
    return (b & 0x80000000u) ? ~b : (b | 0x80000000u);
}
__device__ __forceinline__ float dot2b(unsigned a, unsigned b) {  // 2 packed bf16 pairs
    float a0 = __uint_as_float(a << 16), a1 = __uint_as_float(a & 0xffff0000u);
    float b0 = __uint_as_float(b << 16), b1 = __uint_as_float(b & 0xffff0000u);
    return a0 * b0 + a1 * b1;
}

// ---------------- MFMA bf16 GEMM: C = act(A @ Bt^T + bias) + res ----------------
// A: n x K bf16 (row-major, lda=K); Bt: M x K bf16 (row-major = B transposed).
// M % 128 == 0, K % 32 == 0. grid = (M/128, ceil(n/128)), block = 256.
#define LDSP 40   // padded row stride (ushorts) to break bank conflicts
__global__ __launch_bounds__(256) void gemm_bf16_kernel(
    const ushort* __restrict__ A, int lda,
    const ushort* __restrict__ Bt,
    const float* __restrict__ bias,
    const float* __restrict__ res, int ldr,
    float* __restrict__ Cf, ushort* __restrict__ Cb, int ldc,
    int n, int K, int act)
{
    __shared__ ushort As[128 * LDSP];
    __shared__ ushort Bs[128 * LDSP];
    int tid = threadIdx.x;
    int lane = tid & 63;
    int wave = tid >> 6;
    int wr = wave >> 1, wc = wave & 1;
    int brow = blockIdx.y * 128;
    int bcol = blockIdx.x * 128;

    f32x4 acc[4][4] = {};
    int m0 = lane & 15;
    int koff = (lane >> 4) * 8;

    for (int k0 = 0; k0 < K; k0 += 32) {
        #pragma unroll
        for (int p = 0; p < 2; ++p) {
            int chunk = tid + p * 256;          // 0..511 16B-chunks
            int row = chunk >> 2;               // 0..127
            int col8 = (chunk & 3) * 8;
            int gr = brow + row; if (gr >= n) gr = n - 1;
            *(uint4*)&As[row * LDSP + col8] = *(const uint4*)&A[(long)gr * lda + k0 + col8];
            *(uint4*)&Bs[row * LDSP + col8] = *(const uint4*)&Bt[(long)(bcol + row) * K + k0 + col8];
        }
        __syncthreads();
        short8 af[4], bfr[4];
        #pragma unroll
        for (int i = 0; i < 4; ++i)
            af[i] = *(const short8*)&As[(wr * 64 + i * 16 + m0) * LDSP + koff];
        #pragma unroll
        for (int j = 0; j < 4; ++j)
            bfr[j] = *(const short8*)&Bs[(wc * 64 + j * 16 + m0) * LDSP + koff];
        #pragma unroll
        for (int i = 0; i < 4; ++i)
            #pragma unroll
            for (int j = 0; j < 4; ++j)
                acc[i][j] = __builtin_amdgcn_mfma_f32_16x16x32_bf16(af[i], bfr[j], acc[i][j], 0, 0, 0);
        __syncthreads();
    }

    int crow0 = (lane >> 4) * 4;
    int ccol = lane & 15;
    #pragma unroll
    for (int i = 0; i < 4; ++i) {
        #pragma unroll
        for (int r = 0; r < 4; ++r) {
            int grow = brow + wr * 64 + i * 16 + crow0 + r;
            if (grow >= n) continue;
            #pragma unroll
            for (int j = 0; j < 4; ++j) {
                int gcol = bcol + wc * 64 + j * 16 + ccol;
                float v = acc[i][j][r];
                if (bias) v += bias[gcol];
                if (act) v = gelu_f(v);
                if (res) v += res[(long)grow * ldr + gcol];
                if (Cf) Cf[(long)grow * ldc + gcol] = v;
                if (Cb) Cb[(long)grow * ldc + gcol] = f2b(v);
            }
        }
    }
}

// ---------------- fp32 GEMM (input projection only, K=197) ----------------
__global__ __launch_bounds__(256) void gemm_f32_kernel(
    const float* __restrict__ A, int lda,
    const float* __restrict__ B, int ldb,
    const float* __restrict__ bias, float* __restrict__ C, int ldc,
    int n, int K, int M)
{
    __shared__ float As[16][65];
    __shared__ float Bs[16][64];
    int tid = threadIdx.x;
    int brow = blockIdx.y * 64;
    int bcol = blockIdx.x * 64;
    int tr = tid >> 4, tc = tid & 15;
    float acc[4][4] = {};
    for (int k0 = 0; k0 < K; k0 += 16) {
        #pragma unroll
        for (int i = 0; i < 4; ++i) {
            int idx = tid + i * 256;
            int r = idx >> 4, c = idx & 15;
            int gr = brow + r, gc = k0 + c;
            As[c][r] = (gr < n && gc < K) ? A[(long)gr * lda + gc] : 0.f;
        }
        #pragma unroll
        for (int i = 0; i < 4; ++i) {
            int idx = tid + i * 256;
            int r = idx >> 6, c = idx & 63;
            int gr = k0 + r;
            Bs[r][c] = (gr < K) ? B[(long)gr * ldb + bcol + c] : 0.f;
        }
        __syncthreads();
        #pragma unroll
        for (int kk = 0; kk < 16; ++kk) {
            float a0 = As[kk][tr * 4 + 0], a1 = As[kk][tr * 4 + 1];
            float a2 = As[kk][tr * 4 + 2], a3 = As[kk][tr * 4 + 3];
            float b0 = Bs[kk][tc * 4 + 0], b1 = Bs[kk][tc * 4 + 1];
            float b2 = Bs[kk][tc * 4 + 2], b3 = Bs[kk][tc * 4 + 3];
            acc[0][0] += a0 * b0; acc[0][1] += a0 * b1; acc[0][2] += a0 * b2; acc[0][3] += a0 * b3;
            acc[1][0] += a1 * b0; acc[1][1] += a1 * b1; acc[1][2] += a1 * b2; acc[1][3] += a1 * b3;
            acc[2][0] += a2 * b0; acc[2][1] += a2 * b1; acc[2][2] += a2 * b2; acc[2][3] += a2 * b3;
            acc[3][0] += a3 * b0; acc[3][1] += a3 * b1; acc[3][2] += a3 * b2; acc[3][3] += a3 * b3;
        }
        __syncthreads();
    }
    #pragma unroll
    for (int i = 0; i < 4; ++i) {
        int gr = brow + tr * 4 + i;
        if (gr >= n) continue;
        #pragma unroll
        for (int j = 0; j < 4; ++j) {
            int gc = bcol + tc * 4 + j;
            C[(long)gr * ldc + gc] = acc[i][j] + bias[gc];
        }
    }
}

// ---------------- LayerNorm (rows of 256), fp32 in(+res), fp32/bf16 out ----------------
__global__ __launch_bounds__(256) void ln256_kernel(
    const float* __restrict__ a, const float* __restrict__ res,
    const float* __restrict__ g, const float* __restrict__ bta,
    float* __restrict__ outf, ushort* __restrict__ outb, int n, int post_gelu)
{
    int row = blockIdx.x * 4 + (threadIdx.x >> 6);
    if (row >= n) return;
    int lane = threadIdx.x & 63;
    float4 v = *(const float4*)(a + (long)row * H + lane * 4);
    if (res) {
        float4 r = *(const float4*)(res + (long)row * H + lane * 4);
        v.x += r.x; v.y += r.y; v.z += r.z; v.w += r.w;
    }
    float s = v.x + v.y + v.z + v.w;
    #pragma unroll
    for (int off = 1; off < 64; off <<= 1) s += __shfl_xor(s, off);
    float mean = s * (1.0f / H);
    float dx = v.x - mean, dy = v.y - mean, dz = v.z - mean, dw = v.w - mean;
    float qs = dx * dx + dy * dy + dz * dz + dw * dw;
    #pragma unroll
    for (int off = 1; off < 64; off <<= 1) qs += __shfl_xor(qs, off);
    float rstd = rsqrtf(qs * (1.0f / H) + 1e-5f);
    float4 gg = *(const float4*)(g + lane * 4);
    float4 bb = *(const float4*)(bta + lane * 4);
    float4 o;
    o.x = dx * rstd * gg.x + bb.x;
    o.y = dy * rstd * gg.y + bb.y;
    o.z = dz * rstd * gg.z + bb.z;
    o.w = dw * rstd * gg.w + bb.w;
    if (post_gelu) { o.x = gelu_f(o.x); o.y = gelu_f(o.y); o.z = gelu_f(o.z); o.w = gelu_f(o.w); }
    if (outf) *(float4*)(outf + (long)row * H + lane * 4) = o;
    if (outb) {
        ushort4 ob = { f2b(o.x), f2b(o.y), f2b(o.z), f2b(o.w) };
        *(ushort4*)(outb + (long)row * H + lane * 4) = ob;
    }
}

// ---------------- conversions ----------------
__global__ __launch_bounds__(256) void f2b_kernel(const float* __restrict__ in,
                                                  ushort* __restrict__ out, long n4)
{
    long i = (long)blockIdx.x * 256 + threadIdx.x;
    if (i >= n4) return;
    float4 v = *(const float4*)(in + i * 4);
    ushort4 o = { f2b(v.x), f2b(v.y), f2b(v.z), f2b(v.w) };
    *(ushort4*)(out + i * 4) = o;
}

// W (K x M fp32) -> Wt (M x K bf16)
__global__ __launch_bounds__(256) void wt_kernel(const float* __restrict__ W,
                                                 ushort* __restrict__ Wt, int K, int M)
{
    long i = (long)blockIdx.x * 256 + threadIdx.x;
    if (i >= (long)K * M) return;
    int m = (int)(i % M), k = (int)(i / M);
    Wt[(long)m * K + k] = f2b(W[i]);
}

// ---------------- attention (per group of 4 heads) ----------------
// We/be are the full per-layer pointers; head index hh = g*4 + (i&3).
__global__ __launch_bounds__(256) void score_kernel(
    const ushort* __restrict__ qg, const ushort* __restrict__ kg,
    const int* __restrict__ src, const int* __restrict__ dst,
    const float* __restrict__ ea, const float* __restrict__ We,
    const float* __restrict__ be, int g,
    float* __restrict__ score, unsigned* __restrict__ mxkey)
{
    int i = blockIdx.x * 256 + threadIdx.x;
    if (i >= NE * 4) return;
    int e = i >> 2, hg = i & 3;
    int hh = g * 4 + hg;
    int s = src[e], d = dst[e];
    const uint4* qp = (const uint4*)(qg + (long)d * 128 + hg * 32);
    const uint4* kp = (const uint4*)(kg + (long)s * 128 + hg * 32);
    float acc = 0.f;
    #pragma unroll
    for (int j = 0; j < 4; ++j) {
        uint4 qa = qp[j], ka = kp[j];
        acc += dot2b(qa.x, ka.x) + dot2b(qa.y, ka.y) + dot2b(qa.z, ka.z) + dot2b(qa.w, ka.w);
    }
    float sc = acc * INV_SCALE + ea[e * 2 + 0] * We[hh] + ea[e * 2 + 1] * We[8 + hh] + be[hh];
    score[i] = sc;
    atomicMax(&mxkey[d * 4 + hg], fkey(sc));
}

__global__ __launch_bounds__(256) void ex_kernel(
    float* __restrict__ score, const unsigned* __restrict__ mxkey,
    const int* __restrict__ dst, float* __restrict__ denom)
{
    int i = blockIdx.x * 256 + threadIdx.x;
    if (i >= NE * 4) return;
    int e = i >> 2, hg = i & 3;
    int d = dst[e];
    unsigned k = mxkey[d * 4 + hg];
    float mx = __uint_as_float((k & 0x80000000u) ? (k & 0x7FFFFFFFu) : ~k);
    float ev = expf(score[i] - mx);
    score[i] = ev;
    atomicAdd(&denom[d * 4 + hg], ev);
}

__global__ __launch_bounds__(256) void scatter_kernel(
    const float* __restrict__ ex, const float* __restrict__ denom,
    const ushort* __restrict__ vg, const int* __restrict__ src,
    const int* __restrict__ dst, int g, float* __restrict__ agg)
{
    long i = (long)blockIdx.x * 256 + threadIdx.x;
    if (i >= (long)NE * 32) return;
    int e = (int)(i >> 5);
    int c4 = (int)(i & 31);
    int hg = c4 >> 3;
    int s = src[e], d = dst[e];
    float w = ex[(long)e * 4 + hg] / (denom[(long)d * 4 + hg] + 1e-16f);
    uint2 vv = *(const uint2*)(vg + (long)s * 128 + c4 * 4);
    float v0 = __uint_as_float(vv.x << 16), v1 = __uint_as_float(vv.x & 0xffff0000u);
    float v2 = __uint_as_float(vv.y << 16), v3 = __uint_as_float(vv.y & 0xffff0000u);
    float* ap = agg + (long)d * H + g * 128 + c4 * 4;
    atomicAdd(ap + 0, w * v0);
    atomicAdd(ap + 1, w * v1);
    atomicAdd(ap + 2, w * v2);
    atomicAdd(ap + 3, w * v3);
}

// ---------------- classifier tail ----------------
__global__ __launch_bounds__(256) void cls_kernel(
    const float* __restrict__ t1, const float* __restrict__ W,
    const float* __restrict__ b, float* __restrict__ out)
{
    int i = blockIdx.x * 256 + threadIdx.x;
    if (i >= NN) return;
    const float* tp = t1 + (long)i * 128;
    float a0 = 0.f, a1 = 0.f;
    #pragma unroll
    for (int j = 0; j < 128; j += 4) {
        float4 t = *(const float4*)(tp + j);
        a0 += t.x * W[(j + 0) * 2] + t.y * W[(j + 1) * 2] + t.z * W[(j + 2) * 2] + t.w * W[(j + 3) * 2];
        a1 += t.x * W[(j + 0) * 2 + 1] + t.y * W[(j + 1) * 2 + 1] + t.z * W[(j + 2) * 2 + 1] + t.w * W[(j + 3) * 2 + 1];
    }
    float l0 = a0 + b[0], l1 = a1 + b[1];
    out[(long)i * 2 + 0] = l0;
    out[(long)i * 2 + 1] = l1;
    float m = fmaxf(l0, l1);
    float p0 = expf(l0 - m), p1 = expf(l1 - m);
    float sden = p0 + p1;
    out[2L * NN + (long)i * 2 + 0] = p0 / sden;
    out[2L * NN + (long)i * 2 + 1] = p1 / sden;
}

extern "C" void kernel_launch(void* const* d_in, const int* in_sizes, int n_in,
                              void* d_out, int out_size, void* d_ws, size_t ws_size,
                              hipStream_t stream) {
    const float* x      = (const float*)d_in[0];
    const int*   ei     = (const int*)d_in[1];
    const float* ea     = (const float*)d_in[2];
    const float* in_W   = (const float*)d_in[3];
    const float* in_b   = (const float*)d_in[4];
    const float* in_g   = (const float*)d_in[5];
    const float* in_bb  = (const float*)d_in[6];
    const float* Wq     = (const float*)d_in[7];
    const float* Wk     = (const float*)d_in[8];
    const float* Wv     = (const float*)d_in[9];
    const float* We     = (const float*)d_in[10];
    const float* be     = (const float*)d_in[11];
    const float* Wo     = (const float*)d_in[12];
    const float* bo     = (const float*)d_in[13];
    const float* ln1_g  = (const float*)d_in[14];
    const float* ln1_b  = (const float*)d_in[15];
    const float* ln2_g  = (const float*)d_in[16];
    const float* ln2_b  = (const float*)d_in[17];
    const float* f1_W   = (const float*)d_in[18];
    const float* f1_b   = (const float*)d_in[19];
    const float* f2_W   = (const float*)d_in[20];
    const float* f2_b   = (const float*)d_in[21];
    const float* cls1_W = (const float*)d_in[22];
    const float* cls1_b = (const float*)d_in[23];
    const float* cls2_W = (const float*)d_in[24];
    const float* cls2_b = (const float*)d_in[25];
    float* out = (float*)d_out;

    const int* src = ei;
    const int* dst = ei + NE;

    // ---- workspace layout (~189 MB) ----
    char* w = (char*)d_ws;
    float* B0 = (float*)w;            w += (size_t)NN * H * 4;     // h (fp32)
    float* B2 = (float*)w;            w += (size_t)NN * H * 4;     // agg / WoOut / out (fp32)
    ushort* hb = (ushort*)w;          w += (size_t)NN * H * 2;     // bf16 GEMM A input
    char* pool = w;                   w += (size_t)NN * 128 * 2 * 3 + (size_t)NE * 4 * 4; // 51.2MB union
    ushort* qg = (ushort*)pool;
    ushort* kg = qg + (size_t)NN * 128;
    ushort* vg = kg + (size_t)NN * 128;
    float* score = (float*)(vg + (size_t)NN * 128);                // E*4 fp32
    ushort* tb = (ushort*)pool;                                    // FFN chunk R*1024 bf16
    float* t1 = (float*)pool;                                      // cls NN*128 fp32
    unsigned* mxkey = (unsigned*)w;   w += (size_t)NN * 4 * 4;
    float* denom = (float*)w;         w += (size_t)NN * 4 * 4;
    ushort* wt = (ushort*)w;                                       // bf16 transposed weights

    ushort* wq_t = wt;                         // 5 * 65536
    ushort* wk_t = wq_t + 5L * 65536;
    ushort* wv_t = wk_t + 5L * 65536;
    ushort* wo_t = wv_t + 5L * 65536;
    ushort* f1_t = wo_t + 5L * 65536;          // 5 * 262144
    ushort* f2_t = f1_t + 5L * 262144;         // 5 * 262144
    ushort* c1_t = f2_t + 5L * 262144;         // 32768

    dim3 blk(256);
    const int ln_grid = (NN + 3) / 4;
    const int eh_grid = (NE * 4 + 255) / 256;
    const int sc_grid = (int)(((long)NE * 32 + 255) / 256);
    const int ty = (NN + 127) / 128;

    // ---- convert + transpose all weights to bf16 (once per launch) ----
    for (int l = 0; l < LAYERS; ++l) {
        int g64k = (65536 + 255) / 256, g256k = (262144 + 255) / 256;
        wt_kernel<<<g64k, blk, 0, stream>>>(Wq + (long)l * 65536, wq_t + (long)l * 65536, H, H);
        wt_kernel<<<g64k, blk, 0, stream>>>(Wk + (long)l * 65536, wk_t + (long)l * 65536, H, H);
        wt_kernel<<<g64k, blk, 0, stream>>>(Wv + (long)l * 65536, wv_t + (long)l * 65536, H, H);
        wt_kernel<<<g64k, blk, 0, stream>>>(Wo + (long)l * 65536, wo_t + (long)l * 65536, H, H);
        wt_kernel<<<g256k, blk, 0, stream>>>(f1_W + (long)l * 262144, f1_t + (long)l * 262144, H, FF);
        wt_kernel<<<g256k, blk, 0, stream>>>(f2_W + (long)l * 262144, f2_t + (long)l * 262144, FF, H);
    }
    wt_kernel<<<(32768 + 255) / 256, blk, 0, stream>>>(cls1_W, c1_t, H, 128);

    // ---- input projection ----
    {
        dim3 g(H / 64, (NN + 63) / 64);
        gemm_f32_kernel<<<g, blk, 0, stream>>>(x, FIN, in_W, H, in_b, B2, H, NN, FIN, H);
        ln256_kernel<<<ln_grid, blk, 0, stream>>>(B2, nullptr, in_g, in_bb, B0, nullptr, NN, 1);
    }

    for (int l = 0; l < LAYERS; ++l) {
        const float* we  = We + (long)l * 16;
        const float* bel = be + (long)l * 8;
        const float* bol = bo + (long)l * H;
        const float* g1 = ln1_g + (long)l * H;
        const float* b1 = ln1_b + (long)l * H;
        const float* g2 = ln2_g + (long)l * H;
        const float* b2 = ln2_b + (long)l * H;
        const float* bf1 = f1_b + (long)l * FF;
        const float* bf2 = f2_b + (long)l * H;

        // hb = bf16(LN1(h))
        ln256_kernel<<<ln_grid, blk, 0, stream>>>(B0, nullptr, g1, b1, nullptr, hb, NN, 0);
        hipMemsetAsync(B2, 0, (size_t)NN * H * 4, stream);          // agg = 0

        for (int g = 0; g < 2; ++g) {
            dim3 gq(1, ty);
            gemm_bf16_kernel<<<gq, blk, 0, stream>>>(hb, H, wq_t + (long)l * 65536 + (long)g * 128 * H,
                nullptr, nullptr, 0, nullptr, qg, 128, NN, H, 0);
            gemm_bf16_kernel<<<gq, blk, 0, stream>>>(hb, H, wk_t + (long)l * 65536 + (long)g * 128 * H,
                nullptr, nullptr, 0, nullptr, kg, 128, NN, H, 0);
            gemm_bf16_kernel<<<gq, blk, 0, stream>>>(hb, H, wv_t + (long)l * 65536 + (long)g * 128 * H,
                nullptr, nullptr, 0, nullptr, vg, 128, NN, H, 0);
            hipMemsetAsync(mxkey, 0, (size_t)NN * 4 * 4, stream);
            hipMemsetAsync(denom, 0, (size_t)NN * 4 * 4, stream);
            // NOTE: pass base we/bel — kernel computes hh = g*4+hg itself (round-3 bug was double offset)
            score_kernel<<<eh_grid, blk, 0, stream>>>(qg, kg, src, dst, ea, we, bel, g, score, mxkey);
            ex_kernel<<<eh_grid, blk, 0, stream>>>(score, mxkey, dst, denom);
            scatter_kernel<<<sc_grid, blk, 0, stream>>>(score, denom, vg, src, dst, g, B2);
        }

        // hb = bf16(agg); B2 = hb @ Wo^T + bo; B2 = LN(B2 + h) -> (B2 fp32, hb bf16)
        f2b_kernel<<<(int)(((long)NN * H / 4 + 255) / 256), blk, 0, stream>>>(B2, hb, (long)NN * H / 4);
        dim3 gh(2, ty);
        gemm_bf16_kernel<<<gh, blk, 0, stream>>>(hb, H, wo_t + (long)l * 65536,
            bol, nullptr, 0, B2, nullptr, H, NN, H, 0);
        ln256_kernel<<<ln_grid, blk, 0, stream>>>(B2, B0, g2, b2, B2, hb, NN, 0);

        // FFN row-chunked: tb = gelu(hb@f1^T+b) bf16 ; B0 = tb@f2^T + b + B2
        const int R = 12800;
        for (int r0 = 0; r0 < NN; r0 += R) {
            int nr = (NN - r0 < R) ? (NN - r0) : R;
            int cty = (nr + 127) / 128;
            dim3 gf(8, cty);
            gemm_bf16_kernel<<<gf, blk, 0, stream>>>(hb + (long)r0 * H, H, f1_t + (long)l * 262144,
                bf1, nullptr, 0, nullptr, tb, FF, nr, H, 1);
            dim3 gb(2, cty);
            gemm_bf16_kernel<<<gb, blk, 0, stream>>>(tb, FF, f2_t + (long)l * 262144,
                bf2, B2 + (long)r0 * H, H, B0 + (long)r0 * H, nullptr, H, nr, FF, 0);
        }
    }

    // ---- classifier ----
    f2b_kernel<<<(int)(((long)NN * H / 4 + 255) / 256), blk, 0, stream>>>(B0, hb, (long)NN * H / 4);
    {
        dim3 g(1, ty);
        gemm_bf16_kernel<<<g, blk, 0, stream>>>(hb, H, c1_t, cls1_b, nullptr, 0, t1, nullptr, 128, NN, H, 1);
        cls_kernel<<<(NN + 255) / 256, blk, 0, stream>>>(t1, cls2_W, cls2_b, out);
    }
}

// Round 5
// 4797.182 us; speedup vs baseline: 5.9175x; 3.7715x over previous
//
#include <hip/hip_runtime.h>
#include <math.h>

#define NN 50000
#define NE 800000
#define FIN 197
#define H 256
#define HEADS 8
#define HD 32
#define LAYERS 5
#define FF 1024
#define INV_SCALE 0.17677669529663687f   // 1/sqrt(32)

typedef __attribute__((ext_vector_type(8))) short short8;
typedef __attribute__((ext_vector_type(4))) float f32x4;
typedef unsigned short ushort;

__device__ __forceinline__ float gelu_f(float x) {
    return 0.5f * x * (1.0f + erff(x * 0.7071067811865476f));
}
__device__ __forceinline__ ushort f2b(float f) {        // fp32 -> bf16 RNE
    unsigned u = __float_as_uint(f);
    u += 0x7fffu + ((u >> 16) & 1u);
    return (ushort)(u >> 16);
}
__device__ __forceinline__ float b2f(ushort b) {
    return __uint_as_float(((unsigned)b) << 16);
}
__device__ __forceinline__ float dot2b(unsigned a, unsigned b) {  // 2 packed bf16 pairs
    float a0 = __uint_as_float(a << 16), a1 = __uint_as_float(a & 0xffff0000u);
    float b0 = __uint_as_float(b << 16), b1 = __uint_as_float(b & 0xffff0000u);
    return a0 * b0 + a1 * b1;
}

// ---------------- MFMA bf16 GEMM: C = act(A @ Bt^T + bias) + res ----------------
// A: n x K bf16 (row-major, lda); Bt: M x K bf16 (row-major = B transposed).
// M % 128 == 0, K % 32 == 0. grid = (M/128, ceil(n/128)), block = 256.
#define LDSP 40
__global__ __launch_bounds__(256) void gemm_bf16_kernel(
    const ushort* __restrict__ A, int lda,
    const ushort* __restrict__ Bt,
    const float* __restrict__ bias,
    const float* __restrict__ res, int ldr,
    float* __restrict__ Cf, ushort* __restrict__ Cb, int ldc,
    int n, int K, int act)
{
    __shared__ ushort As[128 * LDSP];
    __shared__ ushort Bs[128 * LDSP];
    int tid = threadIdx.x;
    int lane = tid & 63;
    int wave = tid >> 6;
    int wr = wave >> 1, wc = wave & 1;
    int brow = blockIdx.y * 128;
    int bcol = blockIdx.x * 128;

    f32x4 acc[4][4] = {};
    int m0 = lane & 15;
    int koff = (lane >> 4) * 8;

    for (int k0 = 0; k0 < K; k0 += 32) {
        #pragma unroll
        for (int p = 0; p < 2; ++p) {
            int chunk = tid + p * 256;
            int row = chunk >> 2;
            int col8 = (chunk & 3) * 8;
            int gr = brow + row; if (gr >= n) gr = n - 1;
            *(uint4*)&As[row * LDSP + col8] = *(const uint4*)&A[(long)gr * lda + k0 + col8];
            *(uint4*)&Bs[row * LDSP + col8] = *(const uint4*)&Bt[(long)(bcol + row) * K + k0 + col8];
        }
        __syncthreads();
        short8 af[4], bfr[4];
        #pragma unroll
        for (int i = 0; i < 4; ++i)
            af[i] = *(const short8*)&As[(wr * 64 + i * 16 + m0) * LDSP + koff];
        #pragma unroll
        for (int j = 0; j < 4; ++j)
            bfr[j] = *(const short8*)&Bs[(wc * 64 + j * 16 + m0) * LDSP + koff];
        #pragma unroll
        for (int i = 0; i < 4; ++i)
            #pragma unroll
            for (int j = 0; j < 4; ++j)
                acc[i][j] = __builtin_amdgcn_mfma_f32_16x16x32_bf16(af[i], bfr[j], acc[i][j], 0, 0, 0);
        __syncthreads();
    }

    int crow0 = (lane >> 4) * 4;
    int ccol = lane & 15;
    #pragma unroll
    for (int i = 0; i < 4; ++i) {
        #pragma unroll
        for (int r = 0; r < 4; ++r) {
            int grow = brow + wr * 64 + i * 16 + crow0 + r;
            if (grow >= n) continue;
            #pragma unroll
            for (int j = 0; j < 4; ++j) {
                int gcol = bcol + wc * 64 + j * 16 + ccol;
                float v = acc[i][j][r];
                if (bias) v += bias[gcol];
                if (act) v = gelu_f(v);
                if (res) v += res[(long)grow * ldr + gcol];
                if (Cf) Cf[(long)grow * ldc + gcol] = v;
                if (Cb) Cb[(long)grow * ldc + gcol] = f2b(v);
            }
        }
    }
}

// ---------------- fp32 GEMM (input projection only, K=197) ----------------
__global__ __launch_bounds__(256) void gemm_f32_kernel(
    const float* __restrict__ A, int lda,
    const float* __restrict__ B, int ldb,
    const float* __restrict__ bias, float* __restrict__ C, int ldc,
    int n, int K, int M)
{
    __shared__ float As[16][65];
    __shared__ float Bs[16][64];
    int tid = threadIdx.x;
    int brow = blockIdx.y * 64;
    int bcol = blockIdx.x * 64;
    int tr = tid >> 4, tc = tid & 15;
    float acc[4][4] = {};
    for (int k0 = 0; k0 < K; k0 += 16) {
        #pragma unroll
        for (int i = 0; i < 4; ++i) {
            int idx = tid + i * 256;
            int r = idx >> 4, c = idx & 15;
            int gr = brow + r, gc = k0 + c;
            As[c][r] = (gr < n && gc < K) ? A[(long)gr * lda + gc] : 0.f;
        }
        #pragma unroll
        for (int i = 0; i < 4; ++i) {
            int idx = tid + i * 256;
            int r = idx >> 6, c = idx & 63;
            int gr = k0 + r;
            Bs[r][c] = (gr < K) ? B[(long)gr * ldb + bcol + c] : 0.f;
        }
        __syncthreads();
        #pragma unroll
        for (int kk = 0; kk < 16; ++kk) {
            float a0 = As[kk][tr * 4 + 0], a1 = As[kk][tr * 4 + 1];
            float a2 = As[kk][tr * 4 + 2], a3 = As[kk][tr * 4 + 3];
            float b0 = Bs[kk][tc * 4 + 0], b1 = Bs[kk][tc * 4 + 1];
            float b2 = Bs[kk][tc * 4 + 2], b3 = Bs[kk][tc * 4 + 3];
            acc[0][0] += a0 * b0; acc[0][1] += a0 * b1; acc[0][2] += a0 * b2; acc[0][3] += a0 * b3;
            acc[1][0] += a1 * b0; acc[1][1] += a1 * b1; acc[1][2] += a1 * b2; acc[1][3] += a1 * b3;
            acc[2][0] += a2 * b0; acc[2][1] += a2 * b1; acc[2][2] += a2 * b2; acc[2][3] += a2 * b3;
            acc[3][0] += a3 * b0; acc[3][1] += a3 * b1; acc[3][2] += a3 * b2; acc[3][3] += a3 * b3;
        }
        __syncthreads();
    }
    #pragma unroll
    for (int i = 0; i < 4; ++i) {
        int gr = brow + tr * 4 + i;
        if (gr >= n) continue;
        #pragma unroll
        for (int j = 0; j < 4; ++j) {
            int gc = bcol + tc * 4 + j;
            C[(long)gr * ldc + gc] = acc[i][j] + bias[gc];
        }
    }
}

// ---------------- LayerNorm rows of 256; input fp32 (af) or bf16 (ab) ----------------
__global__ __launch_bounds__(256) void ln256_kernel(
    const float* __restrict__ af, const ushort* __restrict__ ab,
    const float* __restrict__ res,
    const float* __restrict__ g, const float* __restrict__ bta,
    float* __restrict__ outf, ushort* __restrict__ outb, int n, int post_gelu)
{
    int row = blockIdx.x * 4 + (threadIdx.x >> 6);
    if (row >= n) return;
    int lane = threadIdx.x & 63;
    float4 v;
    if (af) {
        v = *(const float4*)(af + (long)row * H + lane * 4);
    } else {
        ushort4 vb = *(const ushort4*)(ab + (long)row * H + lane * 4);
        v.x = b2f(vb.x); v.y = b2f(vb.y); v.z = b2f(vb.z); v.w = b2f(vb.w);
    }
    if (res) {
        float4 r = *(const float4*)(res + (long)row * H + lane * 4);
        v.x += r.x; v.y += r.y; v.z += r.z; v.w += r.w;
    }
    float s = v.x + v.y + v.z + v.w;
    #pragma unroll
    for (int off = 1; off < 64; off <<= 1) s += __shfl_xor(s, off);
    float mean = s * (1.0f / H);
    float dx = v.x - mean, dy = v.y - mean, dz = v.z - mean, dw = v.w - mean;
    float qs = dx * dx + dy * dy + dz * dz + dw * dw;
    #pragma unroll
    for (int off = 1; off < 64; off <<= 1) qs += __shfl_xor(qs, off);
    float rstd = rsqrtf(qs * (1.0f / H) + 1e-5f);
    float4 gg = *(const float4*)(g + lane * 4);
    float4 bb = *(const float4*)(bta + lane * 4);
    float4 o;
    o.x = dx * rstd * gg.x + bb.x;
    o.y = dy * rstd * gg.y + bb.y;
    o.z = dz * rstd * gg.z + bb.z;
    o.w = dw * rstd * gg.w + bb.w;
    if (post_gelu) { o.x = gelu_f(o.x); o.y = gelu_f(o.y); o.z = gelu_f(o.z); o.w = gelu_f(o.w); }
    if (outf) *(float4*)(outf + (long)row * H + lane * 4) = o;
    if (outb) {
        ushort4 ob = { f2b(o.x), f2b(o.y), f2b(o.z), f2b(o.w) };
        *(ushort4*)(outb + (long)row * H + lane * 4) = ob;
    }
}

// ---------------- conversions ----------------
__global__ __launch_bounds__(256) void f2b_kernel(const float* __restrict__ in,
                                                  ushort* __restrict__ out, long n4)
{
    long i = (long)blockIdx.x * 256 + threadIdx.x;
    if (i >= n4) return;
    float4 v = *(const float4*)(in + i * 4);
    ushort4 o = { f2b(v.x), f2b(v.y), f2b(v.z), f2b(v.w) };
    *(ushort4*)(out + i * 4) = o;
}

// Wt[m*K + k] = bf16(W[k*ldW + col0 + m]),  m in [0,Msub), k in [0,K)
__global__ __launch_bounds__(256) void wt2_kernel(const float* __restrict__ W, int ldW,
                                                  int col0, int Msub, int K,
                                                  ushort* __restrict__ Wt)
{
    long i = (long)blockIdx.x * 256 + threadIdx.x;
    if (i >= (long)Msub * K) return;
    int m = (int)(i / K), k = (int)(i % K);
    Wt[i] = f2b(W[(long)k * ldW + col0 + m]);
}

// ---------------- CSR build ----------------
__global__ __launch_bounds__(256) void deg_kernel(const int* __restrict__ dst,
                                                   int* __restrict__ deg)
{
    int e = blockIdx.x * 256 + threadIdx.x;
    if (e >= NE) return;
    atomicAdd(&deg[dst[e]], 1);
}

__global__ __launch_bounds__(256) void scan_kernel(const int* __restrict__ deg,
                                                    int* __restrict__ rowptr)
{
    __shared__ int buf[256];
    __shared__ int carry_s;
    if (threadIdx.x == 0) carry_s = 0;
    __syncthreads();
    for (int base = 0; base < NN; base += 256) {
        int i = base + threadIdx.x;
        int v = (i < NN) ? deg[i] : 0;
        buf[threadIdx.x] = v;
        __syncthreads();
        for (int off = 1; off < 256; off <<= 1) {
            int t = (threadIdx.x >= off) ? buf[threadIdx.x - off] : 0;
            __syncthreads();
            buf[threadIdx.x] += t;
            __syncthreads();
        }
        int carry = carry_s;
        int excl = carry + buf[threadIdx.x] - v;
        if (i < NN) rowptr[i] = excl;
        __syncthreads();
        if (threadIdx.x == 255) carry_s = carry + buf[255];
        __syncthreads();
    }
    if (threadIdx.x == 0) rowptr[NN] = carry_s;
}

__global__ __launch_bounds__(256) void fill_kernel(
    const int* __restrict__ src, const int* __restrict__ dst,
    const float* __restrict__ ea, const int* __restrict__ rowptr,
    int* __restrict__ cursor, int* __restrict__ csr_src,
    float2* __restrict__ csr_ea)
{
    int e = blockIdx.x * 256 + threadIdx.x;
    if (e >= NE) return;
    int d = dst[e];
    int pos = atomicAdd(&cursor[d], 1);
    int j = rowptr[d] + pos;
    csr_src[j] = src[e];
    csr_ea[j] = *(const float2*)(ea + 2 * e);
}

// ---------------- fused gather attention (one wave per node, per head-group) ----------------
// qkv: N x 384 bf16 rows = [q(128) | k(128) | v(128)] for this group.
// Writes aggb[node*256 + g*128 + 2*lane] (bf16, 2 channels per lane).
__global__ __launch_bounds__(256) void attn_kernel(
    const ushort* __restrict__ qkv,
    const int* __restrict__ rowptr, const int* __restrict__ csr_src,
    const float2* __restrict__ csr_ea,
    const float* __restrict__ We, const float* __restrict__ be, int g,
    ushort* __restrict__ aggb)
{
    int node = blockIdx.x * 4 + (threadIdx.x >> 6);
    if (node >= NN) return;
    int lane = threadIdx.x & 63;
    int h = lane >> 4;                 // head within group (0..3)
    int hh = g * 4 + h;                // global head
    float w0 = We[hh], w1 = We[8 + hh], bb = be[hh];

    unsigned q2 = *(const unsigned*)(qkv + (long)node * 384 + lane * 2);
    int jbeg = rowptr[node], jend = rowptr[node + 1];

    float m = -1e30f, l = 0.f, ax = 0.f, ay = 0.f;
    for (int j = jbeg; j < jend; ++j) {
        int s = csr_src[j];
        const ushort* krow = qkv + (long)s * 384 + 128;
        unsigned k2 = *(const unsigned*)(krow + lane * 2);
        float p = dot2b(q2, k2);
        p += __shfl_xor(p, 1);
        p += __shfl_xor(p, 2);
        p += __shfl_xor(p, 4);
        p += __shfl_xor(p, 8);         // sum over 32 channels (16 lanes/head)
        float2 eab = csr_ea[j];
        float sc = p * INV_SCALE + eab.x * w0 + eab.y * w1 + bb;
        unsigned v2 = *(const unsigned*)(krow + 128 + lane * 2);
        float vx = __uint_as_float(v2 << 16);
        float vy = __uint_as_float(v2 & 0xffff0000u);
        float mn = fmaxf(m, sc);
        float scale = __expf(m - mn);
        float e = __expf(sc - mn);
        l = l * scale + e;
        ax = ax * scale + e * vx;
        ay = ay * scale + e * vy;
        m = mn;
    }
    float inv = 1.0f / (l + 1e-16f);
    ushort2 o = { f2b(ax * inv), f2b(ay * inv) };
    *(ushort2*)(aggb + (long)node * 256 + g * 128 + lane * 2) = o;
}

// ---------------- classifier tail ----------------
__global__ __launch_bounds__(256) void cls_kernel(
    const float* __restrict__ t1, const float* __restrict__ W,
    const float* __restrict__ b, float* __restrict__ out)
{
    int i = blockIdx.x * 256 + threadIdx.x;
    if (i >= NN) return;
    const float* tp = t1 + (long)i * 128;
    float a0 = 0.f, a1 = 0.f;
    #pragma unroll
    for (int j = 0; j < 128; j += 4) {
        float4 t = *(const float4*)(tp + j);
        a0 += t.x * W[(j + 0) * 2] + t.y * W[(j + 1) * 2] + t.z * W[(j + 2) * 2] + t.w * W[(j + 3) * 2];
        a1 += t.x * W[(j + 0) * 2 + 1] + t.y * W[(j + 1) * 2 + 1] + t.z * W[(j + 2) * 2 + 1] + t.w * W[(j + 3) * 2 + 1];
    }
    float l0 = a0 + b[0], l1 = a1 + b[1];
    out[(long)i * 2 + 0] = l0;
    out[(long)i * 2 + 1] = l1;
    float mx = fmaxf(l0, l1);
    float p0 = expf(l0 - mx), p1 = expf(l1 - mx);
    float sden = p0 + p1;
    out[2L * NN + (long)i * 2 + 0] = p0 / sden;
    out[2L * NN + (long)i * 2 + 1] = p1 / sden;
}

extern "C" void kernel_launch(void* const* d_in, const int* in_sizes, int n_in,
                              void* d_out, int out_size, void* d_ws, size_t ws_size,
                              hipStream_t stream) {
    const float* x      = (const float*)d_in[0];
    const int*   ei     = (const int*)d_in[1];
    const float* ea     = (const float*)d_in[2];
    const float* in_W   = (const float*)d_in[3];
    const float* in_b   = (const float*)d_in[4];
    const float* in_g   = (const float*)d_in[5];
    const float* in_bb  = (const float*)d_in[6];
    const float* Wq     = (const float*)d_in[7];
    const float* Wk     = (const float*)d_in[8];
    const float* Wv     = (const float*)d_in[9];
    const float* We     = (const float*)d_in[10];
    const float* be     = (const float*)d_in[11];
    const float* Wo     = (const float*)d_in[12];
    const float* bo     = (const float*)d_in[13];
    const float* ln1_g  = (const float*)d_in[14];
    const float* ln1_b  = (const float*)d_in[15];
    const float* ln2_g  = (const float*)d_in[16];
    const float* ln2_b  = (const float*)d_in[17];
    const float* f1_W   = (const float*)d_in[18];
    const float* f1_b   = (const float*)d_in[19];
    const float* f2_W   = (const float*)d_in[20];
    const float* f2_b   = (const float*)d_in[21];
    const float* cls1_W = (const float*)d_in[22];
    const float* cls1_b = (const float*)d_in[23];
    const float* cls2_W = (const float*)d_in[24];
    const float* cls2_b = (const float*)d_in[25];
    float* out = (float*)d_out;

    const int* src = ei;
    const int* dst = ei + NE;

    // ---- workspace layout (~159 MB) ----
    char* w = (char*)d_ws;
    float* B0 = (float*)w;            w += (size_t)NN * H * 4;     // h / out (fp32), 51.2 MB
    ushort* hb = (ushort*)w;          w += (size_t)NN * H * 2;     // bf16 activations, 25.6 MB
    char* pool = w;                   w += (size_t)NN * 384 * 2 + (size_t)NN * 256 * 2; // 64.0 MB
    ushort* qkv  = (ushort*)pool;                                  // N x 384 bf16 (per group)
    ushort* aggb = (ushort*)(pool + (size_t)NN * 384 * 2);         // N x 256 bf16
    float*  tproj = (float*)pool;                                  // input-proj t (51.2 MB)
    ushort* woo  = (ushort*)pool;                                  // Wo out bf16 (25.6 MB)
    ushort* tb   = (ushort*)pool;                                  // FFN chunk bf16 (26.2 MB)
    float*  t1   = (float*)pool;                                   // cls hidden fp32 (25.6 MB)
    int* deg    = (int*)w;            w += (size_t)NN * 4;
    int* cursor = (int*)w;            w += (size_t)NN * 4;
    int* rowptr = (int*)w;            w += (size_t)(NN + 2) * 4;   // +pad for 8B alignment
    int* csr_src = (int*)w;           w += (size_t)NE * 4;
    float2* csr_ea = (float2*)w;      w += (size_t)NE * 8;
    ushort* wqkv_t = (ushort*)w;      w += (size_t)LAYERS * 2 * 384 * 256 * 2;
    ushort* wo_t  = (ushort*)w;       w += (size_t)LAYERS * 65536 * 2;
    ushort* f1_t  = (ushort*)w;       w += (size_t)LAYERS * 262144 * 2;
    ushort* f2_t  = (ushort*)w;       w += (size_t)LAYERS * 262144 * 2;
    ushort* c1_t  = (ushort*)w;       w += (size_t)32768 * 2;

    dim3 blk(256);
    const int ln_grid = (NN + 3) / 4;
    const int e_grid = (NE + 255) / 256;
    const int ty = (NN + 127) / 128;

    // ---- CSR build (once per launch) ----
    hipMemsetAsync(deg, 0, (size_t)NN * 4, stream);
    hipMemsetAsync(cursor, 0, (size_t)NN * 4, stream);
    deg_kernel<<<e_grid, blk, 0, stream>>>(dst, deg);
    scan_kernel<<<1, blk, 0, stream>>>(deg, rowptr);
    fill_kernel<<<e_grid, blk, 0, stream>>>(src, dst, ea, rowptr, cursor, csr_src, csr_ea);

    // ---- weight convert/transpose ----
    for (int l = 0; l < LAYERS; ++l) {
        for (int g = 0; g < 2; ++g) {
            ushort* base = wqkv_t + ((long)(l * 2 + g) * 384) * 256;
            int grd = (128 * 256 + 255) / 256;
            wt2_kernel<<<grd, blk, 0, stream>>>(Wq + (long)l * 65536, 256, g * 128, 128, 256, base);
            wt2_kernel<<<grd, blk, 0, stream>>>(Wk + (long)l * 65536, 256, g * 128, 128, 256, base + 128 * 256);
            wt2_kernel<<<grd, blk, 0, stream>>>(Wv + (long)l * 65536, 256, g * 128, 128, 256, base + 256 * 256);
        }
        wt2_kernel<<<(65536 + 255) / 256, blk, 0, stream>>>(Wo + (long)l * 65536, 256, 0, 256, 256, wo_t + (long)l * 65536);
        wt2_kernel<<<(262144 + 255) / 256, blk, 0, stream>>>(f1_W + (long)l * 262144, 1024, 0, 1024, 256, f1_t + (long)l * 262144);
        wt2_kernel<<<(262144 + 255) / 256, blk, 0, stream>>>(f2_W + (long)l * 262144, 256, 0, 256, 1024, f2_t + (long)l * 262144);
    }
    wt2_kernel<<<(32768 + 255) / 256, blk, 0, stream>>>(cls1_W, 128, 0, 128, 256, c1_t);

    // ---- input projection: tproj = x@in_W + in_b ; B0 = gelu(LN(tproj)) ----
    {
        dim3 g(H / 64, (NN + 63) / 64);
        gemm_f32_kernel<<<g, blk, 0, stream>>>(x, FIN, in_W, H, in_b, tproj, H, NN, FIN, H);
        ln256_kernel<<<ln_grid, blk, 0, stream>>>(tproj, nullptr, nullptr, in_g, in_bb, B0, nullptr, NN, 1);
    }

    for (int l = 0; l < LAYERS; ++l) {
        const float* we  = We + (long)l * 16;
        const float* bel = be + (long)l * 8;
        const float* bol = bo + (long)l * H;
        const float* g1 = ln1_g + (long)l * H;
        const float* b1 = ln1_b + (long)l * H;
        const float* g2 = ln2_g + (long)l * H;
        const float* b2 = ln2_b + (long)l * H;
        const float* bf1 = f1_b + (long)l * FF;
        const float* bf2 = f2_b + (long)l * H;

        // hb = bf16(LN1(h))
        ln256_kernel<<<ln_grid, blk, 0, stream>>>(B0, nullptr, nullptr, g1, b1, nullptr, hb, NN, 0);

        // attention, two head-groups
        for (int g = 0; g < 2; ++g) {
            dim3 gq(3, ty);     // M = 384 (q|k|v stacked)
            gemm_bf16_kernel<<<gq, blk, 0, stream>>>(hb, H,
                wqkv_t + ((long)(l * 2 + g) * 384) * 256,
                nullptr, nullptr, 0, nullptr, qkv, 384, NN, H, 0);
            attn_kernel<<<(NN + 3) / 4, blk, 0, stream>>>(qkv, rowptr, csr_src, csr_ea,
                we, bel, g, aggb);
        }

        // woo = bf16(aggb @ Wo^T + bo); B0 = LN(woo + h) in place; hb = bf16(out)
        dim3 gh(2, ty);
        gemm_bf16_kernel<<<gh, blk, 0, stream>>>(aggb, H, wo_t + (long)l * 65536,
            bol, nullptr, 0, nullptr, woo, H, NN, H, 0);
        ln256_kernel<<<ln_grid, blk, 0, stream>>>(nullptr, woo, B0, g2, b2, B0, hb, NN, 0);

        // FFN row-chunked: tb = gelu(hb@f1^T+b) bf16 ; B0 = tb@f2^T + b + out(B0), in place
        const int R = 12800;
        for (int r0 = 0; r0 < NN; r0 += R) {
            int nr = (NN - r0 < R) ? (NN - r0) : R;
            int cty = (nr + 127) / 128;
            dim3 gf(8, cty);
            gemm_bf16_kernel<<<gf, blk, 0, stream>>>(hb + (long)r0 * H, H, f1_t + (long)l * 262144,
                bf1, nullptr, 0, nullptr, tb, FF, nr, H, 1);
            dim3 gb(2, cty);
            gemm_bf16_kernel<<<gb, blk, 0, stream>>>(tb, FF, f2_t + (long)l * 262144,
                bf2, B0 + (long)r0 * H, H, B0 + (long)r0 * H, nullptr, H, nr, FF, 0);
        }
    }

    // ---- classifier ----
    f2b_kernel<<<(int)(((long)NN * H / 4 + 255) / 256), blk, 0, stream>>>(B0, hb, (long)NN * H / 4);
    {
        dim3 g(1, ty);
        gemm_bf16_kernel<<<g, blk, 0, stream>>>(hb, H, c1_t, cls1_b, nullptr, 0, t1, nullptr, 128, NN, H, 1);
        cls_kernel<<<(NN + 255) / 256, blk, 0, stream>>>(t1, cls2_W, cls2_b, out);
    }
}

// Round 6
// 3179.337 us; speedup vs baseline: 8.9286x; 1.5089x over previous
//
#include <hip/hip_runtime.h>
#include <math.h>

#define NN 50000
#define NE 800000
#define FIN 197
#define H 256
#define HEADS 8
#define HD 32
#define LAYERS 5
#define FF 1024
#define INV_SCALE 0.17677669529663687f   // 1/sqrt(32)

typedef __attribute__((ext_vector_type(8))) short short8;
typedef __attribute__((ext_vector_type(4))) float f32x4;
typedef unsigned short ushort;

__device__ __forceinline__ float gelu_f(float x) {
    return 0.5f * x * (1.0f + erff(x * 0.7071067811865476f));
}
__device__ __forceinline__ ushort f2b(float f) {        // fp32 -> bf16 RNE
    unsigned u = __float_as_uint(f);
    u += 0x7fffu + ((u >> 16) & 1u);
    return (ushort)(u >> 16);
}
__device__ __forceinline__ float b2f(ushort b) {
    return __uint_as_float(((unsigned)b) << 16);
}
__device__ __forceinline__ float dot2b(unsigned a, unsigned b) {  // 2 packed bf16 pairs
    float a0 = __uint_as_float(a << 16), a1 = __uint_as_float(a & 0xffff0000u);
    float b0 = __uint_as_float(b << 16), b1 = __uint_as_float(b & 0xffff0000u);
    return a0 * b0 + a1 * b1;
}

// ---------------- MFMA bf16 GEMM: C = act(A @ Bt^T + bias) + res ----------------
// A: n x K bf16 (row-major, lda); Bt: M x K bf16 (row-major = B transposed).
// M % 128 == 0, K % 32 == 0. grid = (M/128, ceil(n/128)), block = 256.
#define LDSP 40
__global__ __launch_bounds__(256) void gemm_bf16_kernel(
    const ushort* __restrict__ A, int lda,
    const ushort* __restrict__ Bt,
    const float* __restrict__ bias,
    const float* __restrict__ res, int ldr,
    float* __restrict__ Cf, ushort* __restrict__ Cb, int ldc,
    int n, int K, int act)
{
    __shared__ ushort As[128 * LDSP];
    __shared__ ushort Bs[128 * LDSP];
    int tid = threadIdx.x;
    int lane = tid & 63;
    int wave = tid >> 6;
    int wr = wave >> 1, wc = wave & 1;
    int brow = blockIdx.y * 128;
    int bcol = blockIdx.x * 128;

    f32x4 acc[4][4] = {};
    int m0 = lane & 15;
    int koff = (lane >> 4) * 8;

    for (int k0 = 0; k0 < K; k0 += 32) {
        #pragma unroll
        for (int p = 0; p < 2; ++p) {
            int chunk = tid + p * 256;
            int row = chunk >> 2;
            int col8 = (chunk & 3) * 8;
            int gr = brow + row; if (gr >= n) gr = n - 1;
            *(uint4*)&As[row * LDSP + col8] = *(const uint4*)&A[(long)gr * lda + k0 + col8];
            *(uint4*)&Bs[row * LDSP + col8] = *(const uint4*)&Bt[(long)(bcol + row) * K + k0 + col8];
        }
        __syncthreads();
        short8 af[4], bfr[4];
        #pragma unroll
        for (int i = 0; i < 4; ++i)
            af[i] = *(const short8*)&As[(wr * 64 + i * 16 + m0) * LDSP + koff];
        #pragma unroll
        for (int j = 0; j < 4; ++j)
            bfr[j] = *(const short8*)&Bs[(wc * 64 + j * 16 + m0) * LDSP + koff];
        #pragma unroll
        for (int i = 0; i < 4; ++i)
            #pragma unroll
            for (int j = 0; j < 4; ++j)
                acc[i][j] = __builtin_amdgcn_mfma_f32_16x16x32_bf16(af[i], bfr[j], acc[i][j], 0, 0, 0);
        __syncthreads();
    }

    int crow0 = (lane >> 4) * 4;
    int ccol = lane & 15;
    #pragma unroll
    for (int i = 0; i < 4; ++i) {
        #pragma unroll
        for (int r = 0; r < 4; ++r) {
            int grow = brow + wr * 64 + i * 16 + crow0 + r;
            if (grow >= n) continue;
            #pragma unroll
            for (int j = 0; j < 4; ++j) {
                int gcol = bcol + wc * 64 + j * 16 + ccol;
                float v = acc[i][j][r];
                if (bias) v += bias[gcol];
                if (act) v = gelu_f(v);
                if (res) v += res[(long)grow * ldr + gcol];
                if (Cf) Cf[(long)grow * ldc + gcol] = v;
                if (Cb) Cb[(long)grow * ldc + gcol] = f2b(v);
            }
        }
    }
}

// ---------------- fp32 GEMM (input projection only, K=197) ----------------
__global__ __launch_bounds__(256) void gemm_f32_kernel(
    const float* __restrict__ A, int lda,
    const float* __restrict__ B, int ldb,
    const float* __restrict__ bias, float* __restrict__ C, int ldc,
    int n, int K, int M)
{
    __shared__ float As[16][65];
    __shared__ float Bs[16][64];
    int tid = threadIdx.x;
    int brow = blockIdx.y * 64;
    int bcol = blockIdx.x * 64;
    int tr = tid >> 4, tc = tid & 15;
    float acc[4][4] = {};
    for (int k0 = 0; k0 < K; k0 += 16) {
        #pragma unroll
        for (int i = 0; i < 4; ++i) {
            int idx = tid + i * 256;
            int r = idx >> 4, c = idx & 15;
            int gr = brow + r, gc = k0 + c;
            As[c][r] = (gr < n && gc < K) ? A[(long)gr * lda + gc] : 0.f;
        }
        #pragma unroll
        for (int i = 0; i < 4; ++i) {
            int idx = tid + i * 256;
            int r = idx >> 6, c = idx & 63;
            int gr = k0 + r;
            Bs[r][c] = (gr < K) ? B[(long)gr * ldb + bcol + c] : 0.f;
        }
        __syncthreads();
        #pragma unroll
        for (int kk = 0; kk < 16; ++kk) {
            float a0 = As[kk][tr * 4 + 0], a1 = As[kk][tr * 4 + 1];
            float a2 = As[kk][tr * 4 + 2], a3 = As[kk][tr * 4 + 3];
            float b0 = Bs[kk][tc * 4 + 0], b1 = Bs[kk][tc * 4 + 1];
            float b2 = Bs[kk][tc * 4 + 2], b3 = Bs[kk][tc * 4 + 3];
            acc[0][0] += a0 * b0; acc[0][1] += a0 * b1; acc[0][2] += a0 * b2; acc[0][3] += a0 * b3;
            acc[1][0] += a1 * b0; acc[1][1] += a1 * b1; acc[1][2] += a1 * b2; acc[1][3] += a1 * b3;
            acc[2][0] += a2 * b0; acc[2][1] += a2 * b1; acc[2][2] += a2 * b2; acc[2][3] += a2 * b3;
            acc[3][0] += a3 * b0; acc[3][1] += a3 * b1; acc[3][2] += a3 * b2; acc[3][3] += a3 * b3;
        }
        __syncthreads();
    }
    #pragma unroll
    for (int i = 0; i < 4; ++i) {
        int gr = brow + tr * 4 + i;
        if (gr >= n) continue;
        #pragma unroll
        for (int j = 0; j < 4; ++j) {
            int gc = bcol + tc * 4 + j;
            C[(long)gr * ldc + gc] = acc[i][j] + bias[gc];
        }
    }
}

// ---------------- LayerNorm rows of 256; input fp32 (af) or bf16 (ab) ----------------
__global__ __launch_bounds__(256) void ln256_kernel(
    const float* __restrict__ af, const ushort* __restrict__ ab,
    const float* __restrict__ res,
    const float* __restrict__ g, const float* __restrict__ bta,
    float* __restrict__ outf, ushort* __restrict__ outb, int n, int post_gelu)
{
    int row = blockIdx.x * 4 + (threadIdx.x >> 6);
    if (row >= n) return;
    int lane = threadIdx.x & 63;
    float4 v;
    if (af) {
        v = *(const float4*)(af + (long)row * H + lane * 4);
    } else {
        ushort4 vb = *(const ushort4*)(ab + (long)row * H + lane * 4);
        v.x = b2f(vb.x); v.y = b2f(vb.y); v.z = b2f(vb.z); v.w = b2f(vb.w);
    }
    if (res) {
        float4 r = *(const float4*)(res + (long)row * H + lane * 4);
        v.x += r.x; v.y += r.y; v.z += r.z; v.w += r.w;
    }
    float s = v.x + v.y + v.z + v.w;
    #pragma unroll
    for (int off = 1; off < 64; off <<= 1) s += __shfl_xor(s, off);
    float mean = s * (1.0f / H);
    float dx = v.x - mean, dy = v.y - mean, dz = v.z - mean, dw = v.w - mean;
    float qs = dx * dx + dy * dy + dz * dz + dw * dw;
    #pragma unroll
    for (int off = 1; off < 64; off <<= 1) qs += __shfl_xor(qs, off);
    float rstd = rsqrtf(qs * (1.0f / H) + 1e-5f);
    float4 gg = *(const float4*)(g + lane * 4);
    float4 bb = *(const float4*)(bta + lane * 4);
    float4 o;
    o.x = dx * rstd * gg.x + bb.x;
    o.y = dy * rstd * gg.y + bb.y;
    o.z = dz * rstd * gg.z + bb.z;
    o.w = dw * rstd * gg.w + bb.w;
    if (post_gelu) { o.x = gelu_f(o.x); o.y = gelu_f(o.y); o.z = gelu_f(o.z); o.w = gelu_f(o.w); }
    if (outf) *(float4*)(outf + (long)row * H + lane * 4) = o;
    if (outb) {
        ushort4 ob = { f2b(o.x), f2b(o.y), f2b(o.z), f2b(o.w) };
        *(ushort4*)(outb + (long)row * H + lane * 4) = ob;
    }
}

// ---------------- conversions ----------------
__global__ __launch_bounds__(256) void f2b_kernel(const float* __restrict__ in,
                                                  ushort* __restrict__ out, long n4)
{
    long i = (long)blockIdx.x * 256 + threadIdx.x;
    if (i >= n4) return;
    float4 v = *(const float4*)(in + i * 4);
    ushort4 o = { f2b(v.x), f2b(v.y), f2b(v.z), f2b(v.w) };
    *(ushort4*)(out + i * 4) = o;
}

// all-layer QKV transpose: out[l][m(768: q|k|v)][k] = W*[l][k][m&255]
__global__ __launch_bounds__(256) void wtqkv_kernel(
    const float* __restrict__ Wq, const float* __restrict__ Wk,
    const float* __restrict__ Wv, ushort* __restrict__ out)
{
    long i = (long)blockIdx.x * 256 + threadIdx.x;
    if (i >= (long)LAYERS * 768 * 256) return;
    int l = (int)(i / (768 * 256));
    int r = (int)(i % (768 * 256));
    int m = r >> 8, k = r & 255;
    const float* W = (m < 256) ? Wq : ((m < 512) ? Wk : Wv);
    out[i] = f2b(W[(long)l * 65536 + (long)k * 256 + (m & 255)]);
}

// generic per-layer transpose: out[l][m][k] = W[l][k][m]   (L*K*M elements)
__global__ __launch_bounds__(256) void wtgen_kernel(
    const float* __restrict__ W, ushort* __restrict__ out, int L, int K, int M)
{
    long i = (long)blockIdx.x * 256 + threadIdx.x;
    if (i >= (long)L * K * M) return;
    int l = (int)(i / ((long)K * M));
    int r = (int)(i % ((long)K * M));
    int m = r / K, k = r % K;
    out[i] = f2b(W[(long)l * K * M + (long)k * M + m]);
}

// ---------------- CSR build ----------------
__global__ __launch_bounds__(256) void deg_kernel(const int* __restrict__ dst,
                                                   int* __restrict__ deg)
{
    int e = blockIdx.x * 256 + threadIdx.x;
    if (e >= NE) return;
    atomicAdd(&deg[dst[e]], 1);
}

// per-block exclusive scan of 256-chunk + block sum
__global__ __launch_bounds__(256) void scan1_kernel(const int* __restrict__ deg,
                                                     int* __restrict__ rowptr,
                                                     int* __restrict__ bsum)
{
    __shared__ int buf[256];
    int tid = threadIdx.x;
    int i = blockIdx.x * 256 + tid;
    int v = (i < NN) ? deg[i] : 0;
    buf[tid] = v;
    __syncthreads();
    #pragma unroll
    for (int off = 1; off < 256; off <<= 1) {
        int t = (tid >= off) ? buf[tid - off] : 0;
        __syncthreads();
        buf[tid] += t;
        __syncthreads();
    }
    if (i < NN) rowptr[i] = buf[tid] - v;
    if (tid == 255) bsum[blockIdx.x] = buf[255];
}

// single-block exclusive scan of nb (<=256) block sums
__global__ __launch_bounds__(256) void scan2_kernel(int* __restrict__ bsum, int nb)
{
    __shared__ int buf[256];
    int tid = threadIdx.x;
    int v = (tid < nb) ? bsum[tid] : 0;
    buf[tid] = v;
    __syncthreads();
    #pragma unroll
    for (int off = 1; off < 256; off <<= 1) {
        int t = (tid >= off) ? buf[tid - off] : 0;
        __syncthreads();
        buf[tid] += t;
        __syncthreads();
    }
    if (tid < nb) bsum[tid] = buf[tid] - v;
}

__global__ __launch_bounds__(256) void scan3_kernel(int* __restrict__ rowptr,
                                                     const int* __restrict__ bsum)
{
    int i = blockIdx.x * 256 + threadIdx.x;
    if (i < NN) rowptr[i] += bsum[blockIdx.x];
    if (i == 0) rowptr[NN] = NE;     // total degree is a constant
}

__global__ __launch_bounds__(256) void fill_kernel(
    const int* __restrict__ src, const int* __restrict__ dst,
    const float* __restrict__ ea, const int* __restrict__ rowptr,
    int* __restrict__ cursor, int* __restrict__ csr_src,
    float2* __restrict__ csr_ea)
{
    int e = blockIdx.x * 256 + threadIdx.x;
    if (e >= NE) return;
    int d = dst[e];
    int pos = atomicAdd(&cursor[d], 1);
    int j = rowptr[d] + pos;
    csr_src[j] = src[e];
    csr_ea[j] = *(const float2*)(ea + 2 * e);
}

// ---------------- fused gather attention (one wave per node, all 8 heads) ----------------
// qkv: N x 768 bf16 rows = [q(256) | k(256) | v(256)].
// Lane covers 4 channels: c = lane*4 + {0..3}; head = lane>>3 (8 lanes/head).
__global__ __launch_bounds__(256) void attn_kernel(
    const ushort* __restrict__ qkv,
    const int* __restrict__ rowptr, const int* __restrict__ csr_src,
    const float2* __restrict__ csr_ea,
    const float* __restrict__ We, const float* __restrict__ be,
    ushort* __restrict__ aggb)
{
    int node = blockIdx.x * 4 + (threadIdx.x >> 6);
    if (node >= NN) return;
    int lane = threadIdx.x & 63;
    int h = lane >> 3;                 // global head 0..7
    float w0 = We[h], w1 = We[8 + h], bb = be[h];

    uint2 q2 = *(const uint2*)(qkv + (long)node * 768 + lane * 4);
    int jbeg = rowptr[node], jend = rowptr[node + 1];

    float m = -1e30f, l = 0.f;
    float a0 = 0.f, a1 = 0.f, a2 = 0.f, a3 = 0.f;

    // software-pipelined edge loop
    uint2 kN, vN; float2 eaN;
    if (jbeg < jend) {
        int s0 = csr_src[jbeg];
        eaN = csr_ea[jbeg];
        const ushort* kr = qkv + (long)s0 * 768 + 256;
        kN = *(const uint2*)(kr + lane * 4);
        vN = *(const uint2*)(kr + 256 + lane * 4);
    }
    for (int j = jbeg; j < jend; ++j) {
        uint2 k2 = kN, v2 = vN; float2 eab = eaN;
        if (j + 1 < jend) {
            int s1 = csr_src[j + 1];
            eaN = csr_ea[j + 1];
            const ushort* kr = qkv + (long)s1 * 768 + 256;
            kN = *(const uint2*)(kr + lane * 4);
            vN = *(const uint2*)(kr + 256 + lane * 4);
        }
        float p = dot2b(q2.x, k2.x) + dot2b(q2.y, k2.y);
        p += __shfl_xor(p, 1);
        p += __shfl_xor(p, 2);
        p += __shfl_xor(p, 4);         // sum over 8 lanes = 32 channels
        float sc = p * INV_SCALE + eab.x * w0 + eab.y * w1 + bb;
        float vx = __uint_as_float(v2.x << 16);
        float vy = __uint_as_float(v2.x & 0xffff0000u);
        float vz = __uint_as_float(v2.y << 16);
        float vw = __uint_as_float(v2.y & 0xffff0000u);
        float mn = fmaxf(m, sc);
        float scale = __expf(m - mn);
        float e = __expf(sc - mn);
        l = l * scale + e;
        a0 = a0 * scale + e * vx;
        a1 = a1 * scale + e * vy;
        a2 = a2 * scale + e * vz;
        a3 = a3 * scale + e * vw;
        m = mn;
    }
    float inv = 1.0f / (l + 1e-16f);
    ushort4 o = { f2b(a0 * inv), f2b(a1 * inv), f2b(a2 * inv), f2b(a3 * inv) };
    *(ushort4*)(aggb + (long)node * 256 + lane * 4) = o;
}

// ---------------- classifier tail ----------------
__global__ __launch_bounds__(256) void cls_kernel(
    const float* __restrict__ t1, const float* __restrict__ W,
    const float* __restrict__ b, float* __restrict__ out)
{
    int i = blockIdx.x * 256 + threadIdx.x;
    if (i >= NN) return;
    const float* tp = t1 + (long)i * 128;
    float a0 = 0.f, a1 = 0.f;
    #pragma unroll
    for (int j = 0; j < 128; j += 4) {
        float4 t = *(const float4*)(tp + j);
        a0 += t.x * W[(j + 0) * 2] + t.y * W[(j + 1) * 2] + t.z * W[(j + 2) * 2] + t.w * W[(j + 3) * 2];
        a1 += t.x * W[(j + 0) * 2 + 1] + t.y * W[(j + 1) * 2 + 1] + t.z * W[(j + 2) * 2 + 1] + t.w * W[(j + 3) * 2 + 1];
    }
    float l0 = a0 + b[0], l1 = a1 + b[1];
    out[(long)i * 2 + 0] = l0;
    out[(long)i * 2 + 1] = l1;
    float mx = fmaxf(l0, l1);
    float p0 = expf(l0 - mx), p1 = expf(l1 - mx);
    float sden = p0 + p1;
    out[2L * NN + (long)i * 2 + 0] = p0 / sden;
    out[2L * NN + (long)i * 2 + 1] = p1 / sden;
}

extern "C" void kernel_launch(void* const* d_in, const int* in_sizes, int n_in,
                              void* d_out, int out_size, void* d_ws, size_t ws_size,
                              hipStream_t stream) {
    const float* x      = (const float*)d_in[0];
    const int*   ei     = (const int*)d_in[1];
    const float* ea     = (const float*)d_in[2];
    const float* in_W   = (const float*)d_in[3];
    const float* in_b   = (const float*)d_in[4];
    const float* in_g   = (const float*)d_in[5];
    const float* in_bb  = (const float*)d_in[6];
    const float* Wq     = (const float*)d_in[7];
    const float* Wk     = (const float*)d_in[8];
    const float* Wv     = (const float*)d_in[9];
    const float* We     = (const float*)d_in[10];
    const float* be     = (const float*)d_in[11];
    const float* Wo     = (const float*)d_in[12];
    const float* bo     = (const float*)d_in[13];
    const float* ln1_g  = (const float*)d_in[14];
    const float* ln1_b  = (const float*)d_in[15];
    const float* ln2_g  = (const float*)d_in[16];
    const float* ln2_b  = (const float*)d_in[17];
    const float* f1_W   = (const float*)d_in[18];
    const float* f1_b   = (const float*)d_in[19];
    const float* f2_W   = (const float*)d_in[20];
    const float* f2_b   = (const float*)d_in[21];
    const float* cls1_W = (const float*)d_in[22];
    const float* cls1_b = (const float*)d_in[23];
    const float* cls2_W = (const float*)d_in[24];
    const float* cls2_b = (const float*)d_in[25];
    float* out = (float*)d_out;

    const int* src = ei;
    const int* dst = ei + NE;

    // ---- workspace layout (~197 MB) ----
    char* w = (char*)d_ws;
    float* B0 = (float*)w;            w += (size_t)NN * H * 4;       // h / out (fp32), 51.2 MB
    ushort* hb = (ushort*)w;          w += (size_t)NN * H * 2;       // bf16 activations, 25.6 MB
    char* pool = w;                   w += (size_t)NN * 1024 * 2;    // 102.4 MB union
    ushort* qkv  = (ushort*)pool;                                    // N x 768 bf16 (76.8 MB)
    ushort* aggb = (ushort*)(pool + (size_t)NN * 768 * 2);           // N x 256 bf16 (25.6 MB)
    float*  tproj = (float*)pool;                                    // input-proj t (51.2 MB)
    ushort* tb   = (ushort*)pool;                                    // FFN N x 1024 bf16 (102.4 MB)
    float*  t1   = (float*)pool;                                     // cls hidden fp32 (25.6 MB)
    int* deg    = (int*)w;            w += (size_t)NN * 4;
    int* cursor = (int*)w;            w += (size_t)NN * 4;
    int* rowptr = (int*)w;            w += (size_t)(NN + 2) * 4;
    int* bsum   = (int*)w;            w += 1024;
    int* csr_src = (int*)w;           w += (size_t)NE * 4;
    float2* csr_ea = (float2*)w;      w += (size_t)NE * 8;
    ushort* wqkv_t = (ushort*)w;      w += (size_t)LAYERS * 768 * 256 * 2;   // 1.97 MB
    ushort* wo_t  = (ushort*)w;       w += (size_t)LAYERS * 65536 * 2;
    ushort* f1_t  = (ushort*)w;       w += (size_t)LAYERS * 262144 * 2;
    ushort* f2_t  = (ushort*)w;       w += (size_t)LAYERS * 262144 * 2;
    ushort* c1_t  = (ushort*)w;       w += (size_t)32768 * 2;

    dim3 blk(256);
    const int ln_grid = (NN + 3) / 4;
    const int e_grid = (NE + 255) / 256;
    const int n_grid = (NN + 255) / 256;   // 196 blocks
    const int ty = (NN + 127) / 128;

    // ---- CSR build ----
    hipMemsetAsync(deg, 0, (size_t)NN * 4, stream);
    hipMemsetAsync(cursor, 0, (size_t)NN * 4, stream);
    deg_kernel<<<e_grid, blk, 0, stream>>>(dst, deg);
    scan1_kernel<<<n_grid, blk, 0, stream>>>(deg, rowptr, bsum);
    scan2_kernel<<<1, blk, 0, stream>>>(bsum, n_grid);
    scan3_kernel<<<n_grid, blk, 0, stream>>>(rowptr, bsum);
    fill_kernel<<<e_grid, blk, 0, stream>>>(src, dst, ea, rowptr, cursor, csr_src, csr_ea);

    // ---- weight convert/transpose (5 launches) ----
    wtqkv_kernel<<<(int)(((long)LAYERS * 768 * 256 + 255) / 256), blk, 0, stream>>>(Wq, Wk, Wv, wqkv_t);
    wtgen_kernel<<<(int)(((long)LAYERS * 65536 + 255) / 256), blk, 0, stream>>>(Wo, wo_t, LAYERS, 256, 256);
    wtgen_kernel<<<(int)(((long)LAYERS * 262144 + 255) / 256), blk, 0, stream>>>(f1_W, f1_t, LAYERS, 256, 1024);
    wtgen_kernel<<<(int)(((long)LAYERS * 262144 + 255) / 256), blk, 0, stream>>>(f2_W, f2_t, LAYERS, 1024, 256);
    wtgen_kernel<<<(32768 + 255) / 256, blk, 0, stream>>>(cls1_W, c1_t, 1, 256, 128);

    // ---- input projection: tproj = x@in_W + in_b ; B0 = gelu(LN(tproj)) ----
    {
        dim3 g(H / 64, (NN + 63) / 64);
        gemm_f32_kernel<<<g, blk, 0, stream>>>(x, FIN, in_W, H, in_b, tproj, H, NN, FIN, H);
        ln256_kernel<<<ln_grid, blk, 0, stream>>>(tproj, nullptr, nullptr, in_g, in_bb, B0, nullptr, NN, 1);
    }

    for (int l = 0; l < LAYERS; ++l) {
        const float* we  = We + (long)l * 16;
        const float* bel = be + (long)l * 8;
        const float* bol = bo + (long)l * H;
        const float* g1 = ln1_g + (long)l * H;
        const float* b1 = ln1_b + (long)l * H;
        const float* g2 = ln2_g + (long)l * H;
        const float* b2 = ln2_b + (long)l * H;
        const float* bf1 = f1_b + (long)l * FF;
        const float* bf2 = f2_b + (long)l * H;

        // hb = bf16(LN1(h))
        ln256_kernel<<<ln_grid, blk, 0, stream>>>(B0, nullptr, nullptr, g1, b1, nullptr, hb, NN, 0);

        // fused QKV (M=768) + 8-head gather attention
        dim3 gq(6, ty);
        gemm_bf16_kernel<<<gq, blk, 0, stream>>>(hb, H, wqkv_t + (long)l * 768 * 256,
            nullptr, nullptr, 0, nullptr, qkv, 768, NN, H, 0);
        attn_kernel<<<(NN + 3) / 4, blk, 0, stream>>>(qkv, rowptr, csr_src, csr_ea, we, bel, aggb);

        // hb2: B0 = LN(aggb@Wo^T + bo + h); hb = bf16(out)
        dim3 gh(2, ty);
        gemm_bf16_kernel<<<gh, blk, 0, stream>>>(aggb, H, wo_t + (long)l * 65536,
            bol, nullptr, 0, nullptr, qkv, H, NN, H, 0);   // reuse qkv head as woo (bf16 NxH)
        ln256_kernel<<<ln_grid, blk, 0, stream>>>(nullptr, qkv, B0, g2, b2, B0, hb, NN, 0);

        // FFN one-shot: tb = gelu(hb@f1^T+b) bf16 ; B0 = tb@f2^T + b + B0 (in place)
        dim3 gf(8, ty);
        gemm_bf16_kernel<<<gf, blk, 0, stream>>>(hb, H, f1_t + (long)l * 262144,
            bf1, nullptr, 0, nullptr, tb, FF, NN, H, 1);
        dim3 gb(2, ty);
        gemm_bf16_kernel<<<gb, blk, 0, stream>>>(tb, FF, f2_t + (long)l * 262144,
            bf2, B0, H, B0, nullptr, H, NN, FF, 0);
    }

    // ---- classifier ----
    f2b_kernel<<<(int)(((long)NN * H / 4 + 255) / 256), blk, 0, stream>>>(B0, hb, (long)NN * H / 4);
    {
        dim3 g(1, ty);
        gemm_bf16_kernel<<<g, blk, 0, stream>>>(hb, H, c1_t, cls1_b, nullptr, 0, t1, nullptr, 128, NN, H, 1);
        cls_kernel<<<n_grid, blk, 0, stream>>>(t1, cls2_W, cls2_b, out);
    }
}

// Round 7
// 3104.449 us; speedup vs baseline: 9.1440x; 1.0241x over previous
//
#include <hip/hip_runtime.h>
#include <math.h>

#define NN 50000
#define NE 800000
#define FIN 197
#define KIN 224          // FIN zero-padded to multiple of 32
#define H 256
#define HEADS 8
#define HD 32
#define LAYERS 5
#define FF 1024
#define INV_SCALE 0.17677669529663687f   // 1/sqrt(32)

typedef __attribute__((ext_vector_type(8))) short short8;
typedef __attribute__((ext_vector_type(4))) float f32x4;
typedef unsigned short ushort;

__device__ __forceinline__ float gelu_f(float x) {
    return 0.5f * x * (1.0f + erff(x * 0.7071067811865476f));
}
__device__ __forceinline__ ushort f2b(float f) {        // fp32 -> bf16 RNE
    unsigned u = __float_as_uint(f);
    u += 0x7fffu + ((u >> 16) & 1u);
    return (ushort)(u >> 16);
}
__device__ __forceinline__ float b2f(ushort b) {
    return __uint_as_float(((unsigned)b) << 16);
}
__device__ __forceinline__ float dot2b(unsigned a, unsigned b) {  // 2 packed bf16 pairs
    float a0 = __uint_as_float(a << 16), a1 = __uint_as_float(a & 0xffff0000u);
    float b0 = __uint_as_float(b << 16), b1 = __uint_as_float(b & 0xffff0000u);
    return a0 * b0 + a1 * b1;
}

// ---------------- MFMA bf16 GEMM: C = act(A @ Bt^T + bias) + res ----------------
#define LDSP 40
__global__ __launch_bounds__(256) void gemm_bf16_kernel(
    const ushort* __restrict__ A, int lda,
    const ushort* __restrict__ Bt,
    const float* __restrict__ bias,
    const float* __restrict__ res, int ldr,
    float* __restrict__ Cf, ushort* __restrict__ Cb, int ldc,
    int n, int K, int act)
{
    __shared__ ushort As[128 * LDSP];
    __shared__ ushort Bs[128 * LDSP];
    int tid = threadIdx.x;
    int lane = tid & 63;
    int wave = tid >> 6;
    int wr = wave >> 1, wc = wave & 1;
    int brow = blockIdx.y * 128;
    int bcol = blockIdx.x * 128;

    f32x4 acc[4][4] = {};
    int m0 = lane & 15;
    int koff = (lane >> 4) * 8;

    for (int k0 = 0; k0 < K; k0 += 32) {
        #pragma unroll
        for (int p = 0; p < 2; ++p) {
            int chunk = tid + p * 256;
            int row = chunk >> 2;
            int col8 = (chunk & 3) * 8;
            int gr = brow + row; if (gr >= n) gr = n - 1;
            *(uint4*)&As[row * LDSP + col8] = *(const uint4*)&A[(long)gr * lda + k0 + col8];
            *(uint4*)&Bs[row * LDSP + col8] = *(const uint4*)&Bt[(long)(bcol + row) * K + k0 + col8];
        }
        __syncthreads();
        short8 af[4], bfr[4];
        #pragma unroll
        for (int i = 0; i < 4; ++i)
            af[i] = *(const short8*)&As[(wr * 64 + i * 16 + m0) * LDSP + koff];
        #pragma unroll
        for (int j = 0; j < 4; ++j)
            bfr[j] = *(const short8*)&Bs[(wc * 64 + j * 16 + m0) * LDSP + koff];
        #pragma unroll
        for (int i = 0; i < 4; ++i)
            #pragma unroll
            for (int j = 0; j < 4; ++j)
                acc[i][j] = __builtin_amdgcn_mfma_f32_16x16x32_bf16(af[i], bfr[j], acc[i][j], 0, 0, 0);
        __syncthreads();
    }

    int crow0 = (lane >> 4) * 4;
    int ccol = lane & 15;
    #pragma unroll
    for (int i = 0; i < 4; ++i) {
        #pragma unroll
        for (int r = 0; r < 4; ++r) {
            int grow = brow + wr * 64 + i * 16 + crow0 + r;
            if (grow >= n) continue;
            #pragma unroll
            for (int j = 0; j < 4; ++j) {
                int gcol = bcol + wc * 64 + j * 16 + ccol;
                float v = acc[i][j][r];
                if (bias) v += bias[gcol];
                if (act) v = gelu_f(v);
                if (res) v += res[(long)grow * ldr + gcol];
                if (Cf) Cf[(long)grow * ldc + gcol] = v;
                if (Cb) Cb[(long)grow * ldc + gcol] = f2b(v);
            }
        }
    }
}

// ---------------- LayerNorm rows of 256; input fp32 (af) or bf16 (ab) ----------------
__global__ __launch_bounds__(256) void ln256_kernel(
    const float* __restrict__ af, const ushort* __restrict__ ab,
    const float* __restrict__ res,
    const float* __restrict__ g, const float* __restrict__ bta,
    float* __restrict__ outf, ushort* __restrict__ outb, int n, int post_gelu)
{
    int row = blockIdx.x * 4 + (threadIdx.x >> 6);
    if (row >= n) return;
    int lane = threadIdx.x & 63;
    float4 v;
    if (af) {
        v = *(const float4*)(af + (long)row * H + lane * 4);
    } else {
        ushort4 vb = *(const ushort4*)(ab + (long)row * H + lane * 4);
        v.x = b2f(vb.x); v.y = b2f(vb.y); v.z = b2f(vb.z); v.w = b2f(vb.w);
    }
    if (res) {
        float4 r = *(const float4*)(res + (long)row * H + lane * 4);
        v.x += r.x; v.y += r.y; v.z += r.z; v.w += r.w;
    }
    float s = v.x + v.y + v.z + v.w;
    #pragma unroll
    for (int off = 1; off < 64; off <<= 1) s += __shfl_xor(s, off);
    float mean = s * (1.0f / H);
    float dx = v.x - mean, dy = v.y - mean, dz = v.z - mean, dw = v.w - mean;
    float qs = dx * dx + dy * dy + dz * dz + dw * dw;
    #pragma unroll
    for (int off = 1; off < 64; off <<= 1) qs += __shfl_xor(qs, off);
    float rstd = rsqrtf(qs * (1.0f / H) + 1e-5f);
    float4 gg = *(const float4*)(g + lane * 4);
    float4 bb = *(const float4*)(bta + lane * 4);
    float4 o;
    o.x = dx * rstd * gg.x + bb.x;
    o.y = dy * rstd * gg.y + bb.y;
    o.z = dz * rstd * gg.z + bb.z;
    o.w = dw * rstd * gg.w + bb.w;
    if (post_gelu) { o.x = gelu_f(o.x); o.y = gelu_f(o.y); o.z = gelu_f(o.z); o.w = gelu_f(o.w); }
    if (outf) *(float4*)(outf + (long)row * H + lane * 4) = o;
    if (outb) {
        ushort4 ob = { f2b(o.x), f2b(o.y), f2b(o.z), f2b(o.w) };
        *(ushort4*)(outb + (long)row * H + lane * 4) = ob;
    }
}

// ---------------- conversions ----------------
// x (N x 197 fp32) -> xb (N x 224 bf16, zero-padded cols)
__global__ __launch_bounds__(256) void xcast_kernel(const float* __restrict__ x,
                                                    ushort* __restrict__ xb)
{
    long i = (long)blockIdx.x * 256 + threadIdx.x;
    if (i >= (long)NN * KIN) return;
    int n = (int)(i / KIN), c = (int)(i % KIN);
    xb[i] = (c < FIN) ? f2b(x[(long)n * FIN + c]) : (ushort)0;
}

// in_W (197 x 256 fp32) -> Wt (256 x 224 bf16, zero-padded k)
__global__ __launch_bounds__(256) void wtin_kernel(const float* __restrict__ W,
                                                   ushort* __restrict__ Wt)
{
    int i = blockIdx.x * 256 + threadIdx.x;
    if (i >= 256 * KIN) return;
    int m = i / KIN, k = i % KIN;
    Wt[i] = (k < FIN) ? f2b(W[(long)k * H + m]) : (ushort)0;
}

// all-layer QKV transpose: out[l][m(768: q|k|v)][k] = W*[l][k][m&255]
__global__ __launch_bounds__(256) void wtqkv_kernel(
    const float* __restrict__ Wq, const float* __restrict__ Wk,
    const float* __restrict__ Wv, ushort* __restrict__ out)
{
    long i = (long)blockIdx.x * 256 + threadIdx.x;
    if (i >= (long)LAYERS * 768 * 256) return;
    int l = (int)(i / (768 * 256));
    int r = (int)(i % (768 * 256));
    int m = r >> 8, k = r & 255;
    const float* W = (m < 256) ? Wq : ((m < 512) ? Wk : Wv);
    out[i] = f2b(W[(long)l * 65536 + (long)k * 256 + (m & 255)]);
}

// generic per-layer transpose: out[l][m][k] = W[l][k][m]
__global__ __launch_bounds__(256) void wtgen_kernel(
    const float* __restrict__ W, ushort* __restrict__ out, int L, int K, int M)
{
    long i = (long)blockIdx.x * 256 + threadIdx.x;
    if (i >= (long)L * K * M) return;
    int l = (int)(i / ((long)K * M));
    int r = (int)(i % ((long)K * M));
    int m = r / K, k = r % K;
    out[i] = f2b(W[(long)l * K * M + (long)k * M + m]);
}

// ---------------- CSR build ----------------
__global__ __launch_bounds__(256) void deg_kernel(const int* __restrict__ dst,
                                                   int* __restrict__ deg)
{
    int e = blockIdx.x * 256 + threadIdx.x;
    if (e >= NE) return;
    atomicAdd(&deg[dst[e]], 1);
}

__global__ __launch_bounds__(256) void scan1_kernel(const int* __restrict__ deg,
                                                     int* __restrict__ rowptr,
                                                     int* __restrict__ bsum)
{
    __shared__ int buf[256];
    int tid = threadIdx.x;
    int i = blockIdx.x * 256 + tid;
    int v = (i < NN) ? deg[i] : 0;
    buf[tid] = v;
    __syncthreads();
    #pragma unroll
    for (int off = 1; off < 256; off <<= 1) {
        int t = (tid >= off) ? buf[tid - off] : 0;
        __syncthreads();
        buf[tid] += t;
        __syncthreads();
    }
    if (i < NN) rowptr[i] = buf[tid] - v;
    if (tid == 255) bsum[blockIdx.x] = buf[255];
}

__global__ __launch_bounds__(256) void scan2_kernel(int* __restrict__ bsum, int nb)
{
    __shared__ int buf[256];
    int tid = threadIdx.x;
    int v = (tid < nb) ? bsum[tid] : 0;
    buf[tid] = v;
    __syncthreads();
    #pragma unroll
    for (int off = 1; off < 256; off <<= 1) {
        int t = (tid >= off) ? buf[tid - off] : 0;
        __syncthreads();
        buf[tid] += t;
        __syncthreads();
    }
    if (tid < nb) bsum[tid] = buf[tid] - v;
}

__global__ __launch_bounds__(256) void scan3_kernel(int* __restrict__ rowptr,
                                                     const int* __restrict__ bsum)
{
    int i = blockIdx.x * 256 + threadIdx.x;
    if (i < NN) rowptr[i] += bsum[blockIdx.x];
    if (i == 0) rowptr[NN] = NE;
}

__global__ __launch_bounds__(256) void fill_kernel(
    const int* __restrict__ src, const int* __restrict__ dst,
    const float* __restrict__ ea, const int* __restrict__ rowptr,
    int* __restrict__ cursor, int* __restrict__ csr_src,
    float2* __restrict__ csr_ea)
{
    int e = blockIdx.x * 256 + threadIdx.x;
    if (e >= NE) return;
    int d = dst[e];
    int pos = atomicAdd(&cursor[d], 1);
    int j = rowptr[d] + pos;
    csr_src[j] = src[e];
    csr_ea[j] = *(const float2*)(ea + 2 * e);
}

// ---------------- fused gather attention, dual-stream online softmax ----------------
// qkv: N x 768 bf16 rows = [q(256) | k(256) | v(256)].
// One wave per node; lane covers 4 channels; head = lane>>3 (8 lanes/head).
// Edge list split in two halves with independent online-softmax state (2x MLP),
// merged at the end.
__global__ __launch_bounds__(256) void attn_kernel(
    const ushort* __restrict__ qkv,
    const int* __restrict__ rowptr, const int* __restrict__ csr_src,
    const float2* __restrict__ csr_ea,
    const float* __restrict__ We, const float* __restrict__ be,
    ushort* __restrict__ aggb)
{
    int node = blockIdx.x * 4 + (threadIdx.x >> 6);
    if (node >= NN) return;
    int lane = threadIdx.x & 63;
    int h = lane >> 3;
    float w0 = We[h], w1 = We[8 + h], bb = be[h];

    uint2 q2 = *(const uint2*)(qkv + (long)node * 768 + lane * 4);
    int jbeg = rowptr[node], jend = rowptr[node + 1];
    int len = jend - jbeg;
    int half = len >> 1;
    int jA = jbeg, endA = jbeg + half;       // stream A: half edges
    int jB = endA;                           // stream B: len-half >= half

    float mA = -1e30f, lA = 0.f, aA0 = 0.f, aA1 = 0.f, aA2 = 0.f, aA3 = 0.f;
    float mB = -1e30f, lB = 0.f, aB0 = 0.f, aB1 = 0.f, aB2 = 0.f, aB3 = 0.f;

    int nB = jend - endA;
    for (int t = 0; t < nB; ++t) {
        bool hasA = (jA < endA);
        int sB = csr_src[jB];
        float2 eB = csr_ea[jB];
        int sA = hasA ? csr_src[jA] : sB;
        float2 eA = hasA ? csr_ea[jA] : eB;
        const ushort* krB = qkv + (long)sB * 768 + 256;
        const ushort* krA = qkv + (long)sA * 768 + 256;
        uint2 kB = *(const uint2*)(krB + lane * 4);
        uint2 vB = *(const uint2*)(krB + 256 + lane * 4);
        uint2 kA = *(const uint2*)(krA + lane * 4);
        uint2 vA = *(const uint2*)(krA + 256 + lane * 4);

        // stream B (always valid)
        {
            float p = dot2b(q2.x, kB.x) + dot2b(q2.y, kB.y);
            p += __shfl_xor(p, 1);
            p += __shfl_xor(p, 2);
            p += __shfl_xor(p, 4);
            float sc = p * INV_SCALE + eB.x * w0 + eB.y * w1 + bb;
            float vx = __uint_as_float(vB.x << 16);
            float vy = __uint_as_float(vB.x & 0xffff0000u);
            float vz = __uint_as_float(vB.y << 16);
            float vw = __uint_as_float(vB.y & 0xffff0000u);
            float mn = fmaxf(mB, sc);
            float scale = __expf(mB - mn);
            float e = __expf(sc - mn);
            lB = lB * scale + e;
            aB0 = aB0 * scale + e * vx;
            aB1 = aB1 * scale + e * vy;
            aB2 = aB2 * scale + e * vz;
            aB3 = aB3 * scale + e * vw;
            mB = mn;
            ++jB;
        }
        // stream A
        if (hasA) {
            float p = dot2b(q2.x, kA.x) + dot2b(q2.y, kA.y);
            p += __shfl_xor(p, 1);
            p += __shfl_xor(p, 2);
            p += __shfl_xor(p, 4);
            float sc = p * INV_SCALE + eA.x * w0 + eA.y * w1 + bb;
            float vx = __uint_as_float(vA.x << 16);
            float vy = __uint_as_float(vA.x & 0xffff0000u);
            float vz = __uint_as_float(vA.y << 16);
            float vw = __uint_as_float(vA.y & 0xffff0000u);
            float mn = fmaxf(mA, sc);
            float scale = __expf(mA - mn);
            float e = __expf(sc - mn);
            lA = lA * scale + e;
            aA0 = aA0 * scale + e * vx;
            aA1 = aA1 * scale + e * vy;
            aA2 = aA2 * scale + e * vz;
            aA3 = aA3 * scale + e * vw;
            mA = mn;
            ++jA;
        }
    }

    // merge streams
    float mn = fmaxf(mA, mB);
    float sA = __expf(mA - mn), sB2 = __expf(mB - mn);
    float l = lA * sA + lB * sB2;
    float a0 = aA0 * sA + aB0 * sB2;
    float a1 = aA1 * sA + aB1 * sB2;
    float a2 = aA2 * sA + aB2 * sB2;
    float a3 = aA3 * sA + aB3 * sB2;

    float inv = 1.0f / (l + 1e-16f);
    ushort4 o = { f2b(a0 * inv), f2b(a1 * inv), f2b(a2 * inv), f2b(a3 * inv) };
    *(ushort4*)(aggb + (long)node * 256 + lane * 4) = o;
}

// ---------------- classifier tail (reads bf16 hidden) ----------------
__global__ __launch_bounds__(256) void cls_kernel(
    const float* __restrict__ t1, const float* __restrict__ W,
    const float* __restrict__ b, float* __restrict__ out)
{
    int i = blockIdx.x * 256 + threadIdx.x;
    if (i >= NN) return;
    const float* tp = t1 + (long)i * 128;
    float a0 = 0.f, a1 = 0.f;
    #pragma unroll
    for (int j = 0; j < 128; j += 4) {
        float4 t = *(const float4*)(tp + j);
        a0 += t.x * W[(j + 0) * 2] + t.y * W[(j + 1) * 2] + t.z * W[(j + 2) * 2] + t.w * W[(j + 3) * 2];
        a1 += t.x * W[(j + 0) * 2 + 1] + t.y * W[(j + 1) * 2 + 1] + t.z * W[(j + 2) * 2 + 1] + t.w * W[(j + 3) * 2 + 1];
    }
    float l0 = a0 + b[0], l1 = a1 + b[1];
    out[(long)i * 2 + 0] = l0;
    out[(long)i * 2 + 1] = l1;
    float mx = fmaxf(l0, l1);
    float p0 = expf(l0 - mx), p1 = expf(l1 - mx);
    float sden = p0 + p1;
    out[2L * NN + (long)i * 2 + 0] = p0 / sden;
    out[2L * NN + (long)i * 2 + 1] = p1 / sden;
}

extern "C" void kernel_launch(void* const* d_in, const int* in_sizes, int n_in,
                              void* d_out, int out_size, void* d_ws, size_t ws_size,
                              hipStream_t stream) {
    const float* x      = (const float*)d_in[0];
    const int*   ei     = (const int*)d_in[1];
    const float* ea     = (const float*)d_in[2];
    const float* in_W   = (const float*)d_in[3];
    const float* in_b   = (const float*)d_in[4];
    const float* in_g   = (const float*)d_in[5];
    const float* in_bb  = (const float*)d_in[6];
    const float* Wq     = (const float*)d_in[7];
    const float* Wk     = (const float*)d_in[8];
    const float* Wv     = (const float*)d_in[9];
    const float* We     = (const float*)d_in[10];
    const float* be     = (const float*)d_in[11];
    const float* Wo     = (const float*)d_in[12];
    const float* bo     = (const float*)d_in[13];
    const float* ln1_g  = (const float*)d_in[14];
    const float* ln1_b  = (const float*)d_in[15];
    const float* ln2_g  = (const float*)d_in[16];
    const float* ln2_b  = (const float*)d_in[17];
    const float* f1_W   = (const float*)d_in[18];
    const float* f1_b   = (const float*)d_in[19];
    const float* f2_W   = (const float*)d_in[20];
    const float* f2_b   = (const float*)d_in[21];
    const float* cls1_W = (const float*)d_in[22];
    const float* cls1_b = (const float*)d_in[23];
    const float* cls2_W = (const float*)d_in[24];
    const float* cls2_b = (const float*)d_in[25];
    float* out = (float*)d_out;

    const int* src = ei;
    const int* dst = ei + NE;

    // ---- workspace layout (~197 MB) ----
    char* w = (char*)d_ws;
    float* B0 = (float*)w;            w += (size_t)NN * H * 4;       // h / out (fp32)
    ushort* hb = (ushort*)w;          w += (size_t)NN * H * 2;       // bf16 activations
    char* pool = w;                   w += (size_t)NN * 1024 * 2;    // 102.4 MB union
    ushort* qkv  = (ushort*)pool;                                    // N x 768 bf16
    ushort* aggb = (ushort*)(pool + (size_t)NN * 768 * 2);           // N x 256 bf16
    float*  tproj = (float*)pool;                                    // input-proj t (51.2 MB)
    ushort* xb   = (ushort*)(pool + (size_t)NN * H * 4);             // N x 224 bf16 (22.4 MB)
    ushort* tb   = (ushort*)pool;                                    // FFN N x 1024 bf16
    float*  t1   = (float*)pool;                                     // cls hidden fp32
    int* deg    = (int*)w;            w += (size_t)NN * 4;
    int* cursor = (int*)w;            w += (size_t)NN * 4;
    int* rowptr = (int*)w;            w += (size_t)(NN + 2) * 4;
    int* bsum   = (int*)w;            w += 1024;
    int* csr_src = (int*)w;           w += (size_t)NE * 4;
    float2* csr_ea = (float2*)w;      w += (size_t)NE * 8;
    ushort* wqkv_t = (ushort*)w;      w += (size_t)LAYERS * 768 * 256 * 2;
    ushort* wo_t  = (ushort*)w;       w += (size_t)LAYERS * 65536 * 2;
    ushort* f1_t  = (ushort*)w;       w += (size_t)LAYERS * 262144 * 2;
    ushort* f2_t  = (ushort*)w;       w += (size_t)LAYERS * 262144 * 2;
    ushort* c1_t  = (ushort*)w;       w += (size_t)32768 * 2;
    ushort* inw_t = (ushort*)w;       w += (size_t)256 * KIN * 2;

    dim3 blk(256);
    const int ln_grid = (NN + 3) / 4;
    const int e_grid = (NE + 255) / 256;
    const int n_grid = (NN + 255) / 256;
    const int ty = (NN + 127) / 128;

    // ---- CSR build ----
    hipMemsetAsync(deg, 0, (size_t)NN * 4, stream);
    hipMemsetAsync(cursor, 0, (size_t)NN * 4, stream);
    deg_kernel<<<e_grid, blk, 0, stream>>>(dst, deg);
    scan1_kernel<<<n_grid, blk, 0, stream>>>(deg, rowptr, bsum);
    scan2_kernel<<<1, blk, 0, stream>>>(bsum, n_grid);
    scan3_kernel<<<n_grid, blk, 0, stream>>>(rowptr, bsum);
    fill_kernel<<<e_grid, blk, 0, stream>>>(src, dst, ea, rowptr, cursor, csr_src, csr_ea);

    // ---- weight convert/transpose ----
    wtqkv_kernel<<<(int)(((long)LAYERS * 768 * 256 + 255) / 256), blk, 0, stream>>>(Wq, Wk, Wv, wqkv_t);
    wtgen_kernel<<<(int)(((long)LAYERS * 65536 + 255) / 256), blk, 0, stream>>>(Wo, wo_t, LAYERS, 256, 256);
    wtgen_kernel<<<(int)(((long)LAYERS * 262144 + 255) / 256), blk, 0, stream>>>(f1_W, f1_t, LAYERS, 256, 1024);
    wtgen_kernel<<<(int)(((long)LAYERS * 262144 + 255) / 256), blk, 0, stream>>>(f2_W, f2_t, LAYERS, 1024, 256);
    wtgen_kernel<<<(32768 + 255) / 256, blk, 0, stream>>>(cls1_W, c1_t, 1, 256, 128);
    wtin_kernel<<<(256 * KIN + 255) / 256, blk, 0, stream>>>(in_W, inw_t);

    // ---- input projection (MFMA): xb = bf16(pad(x)); tproj = xb@inW^T + b; B0 = gelu(LN(tproj)) ----
    xcast_kernel<<<(int)(((long)NN * KIN + 255) / 256), blk, 0, stream>>>(x, xb);
    {
        dim3 g(2, ty);
        gemm_bf16_kernel<<<g, blk, 0, stream>>>(xb, KIN, inw_t, in_b, nullptr, 0,
                                                tproj, nullptr, H, NN, KIN, 0);
        ln256_kernel<<<ln_grid, blk, 0, stream>>>(tproj, nullptr, nullptr, in_g, in_bb, B0, nullptr, NN, 1);
    }

    for (int l = 0; l < LAYERS; ++l) {
        const float* we  = We + (long)l * 16;
        const float* bel = be + (long)l * 8;
        const float* bol = bo + (long)l * H;
        const float* g1 = ln1_g + (long)l * H;
        const float* b1 = ln1_b + (long)l * H;
        const float* g2 = ln2_g + (long)l * H;
        const float* b2 = ln2_b + (long)l * H;
        const float* bf1 = f1_b + (long)l * FF;
        const float* bf2 = f2_b + (long)l * H;

        // hb = bf16(LN1(h))
        ln256_kernel<<<ln_grid, blk, 0, stream>>>(B0, nullptr, nullptr, g1, b1, nullptr, hb, NN, 0);

        // fused QKV (M=768) + 8-head gather attention
        dim3 gq(6, ty);
        gemm_bf16_kernel<<<gq, blk, 0, stream>>>(hb, H, wqkv_t + (long)l * 768 * 256,
            nullptr, nullptr, 0, nullptr, qkv, 768, NN, H, 0);
        attn_kernel<<<(NN + 3) / 4, blk, 0, stream>>>(qkv, rowptr, csr_src, csr_ea, we, bel, aggb);

        // B0 = LN(aggb@Wo^T + bo + h); hb = bf16(out)
        dim3 gh(2, ty);
        gemm_bf16_kernel<<<gh, blk, 0, stream>>>(aggb, H, wo_t + (long)l * 65536,
            bol, nullptr, 0, nullptr, qkv, H, NN, H, 0);   // reuse qkv head as woo
        ln256_kernel<<<ln_grid, blk, 0, stream>>>(nullptr, qkv, B0, g2, b2, B0, hb, NN, 0);

        // FFN one-shot: tb = gelu(hb@f1^T+b) bf16 ; B0 = tb@f2^T + b + B0
        dim3 gf(8, ty);
        gemm_bf16_kernel<<<gf, blk, 0, stream>>>(hb, H, f1_t + (long)l * 262144,
            bf1, nullptr, 0, nullptr, tb, FF, NN, H, 1);
        dim3 gb(2, ty);
        // last layer also emits bf16 hidden directly for the classifier
        gemm_bf16_kernel<<<gb, blk, 0, stream>>>(tb, FF, f2_t + (long)l * 262144,
            bf2, B0, H, B0, (l == LAYERS - 1) ? hb : nullptr, H, NN, FF, 0);
    }

    // ---- classifier ----
    {
        dim3 g(1, ty);
        gemm_bf16_kernel<<<g, blk, 0, stream>>>(hb, H, c1_t, cls1_b, nullptr, 0, t1, nullptr, 128, NN, H, 1);
        cls_kernel<<<n_grid, blk, 0, stream>>>(t1, cls2_W, cls2_b, out);
    }
}

// Round 8
// 2998.974 us; speedup vs baseline: 9.4656x; 1.0352x over previous
//
#include <hip/hip_runtime.h>
#include <math.h>

#define NN 50000
#define NE 800000
#define FIN 197
#define KIN 224          // FIN zero-padded to multiple of 32
#define H 256
#define HEADS 8
#define HD 32
#define LAYERS 5
#define FF 1024
#define INV_SCALE 0.17677669529663687f   // 1/sqrt(32)

typedef __attribute__((ext_vector_type(8))) short short8;
typedef __attribute__((ext_vector_type(4))) float f32x4;
typedef unsigned short ushort;

// fast GELU: x * sigmoid(1.59577*(x+0.044715 x^3)) via exp2/rcp.
// max abs err vs exact-erf gelu ~3e-4 — well inside bf16 tolerance.
__device__ __forceinline__ float gelu_f(float x) {
    float x2 = x * x;
    float u = __builtin_fmaf(0.044715f * x2, x, x);
    float e = __builtin_amdgcn_exp2f(-2.3022075f * u);
    return x * __builtin_amdgcn_rcpf(1.0f + e);
}
__device__ __forceinline__ ushort f2b(float f) {        // fp32 -> bf16 RNE
    unsigned u = __float_as_uint(f);
    u += 0x7fffu + ((u >> 16) & 1u);
    return (ushort)(u >> 16);
}
__device__ __forceinline__ float b2f(ushort b) {
    return __uint_as_float(((unsigned)b) << 16);
}
__device__ __forceinline__ float dot2b(unsigned a, unsigned b) {  // 2 packed bf16 pairs
    float a0 = __uint_as_float(a << 16), a1 = __uint_as_float(a & 0xffff0000u);
    float b0 = __uint_as_float(b << 16), b1 = __uint_as_float(b & 0xffff0000u);
    return a0 * b0 + a1 * b1;
}

// ---------------- MFMA bf16 GEMM: C = act(A @ Bt^T + bias) + res ----------------
#define LDSP 40
__global__ __launch_bounds__(256) void gemm_bf16_kernel(
    const ushort* __restrict__ A, int lda,
    const ushort* __restrict__ Bt,
    const float* __restrict__ bias,
    const float* __restrict__ res, int ldr,
    float* __restrict__ Cf, ushort* __restrict__ Cb, int ldc,
    int n, int K, int act)
{
    __shared__ ushort As[128 * LDSP];
    __shared__ ushort Bs[128 * LDSP];
    int tid = threadIdx.x;
    int lane = tid & 63;
    int wave = tid >> 6;
    int wr = wave >> 1, wc = wave & 1;
    int brow = blockIdx.y * 128;
    int bcol = blockIdx.x * 128;

    f32x4 acc[4][4] = {};
    int m0 = lane & 15;
    int koff = (lane >> 4) * 8;

    for (int k0 = 0; k0 < K; k0 += 32) {
        #pragma unroll
        for (int p = 0; p < 2; ++p) {
            int chunk = tid + p * 256;
            int row = chunk >> 2;
            int col8 = (chunk & 3) * 8;
            int gr = brow + row; if (gr >= n) gr = n - 1;
            *(uint4*)&As[row * LDSP + col8] = *(const uint4*)&A[(long)gr * lda + k0 + col8];
            *(uint4*)&Bs[row * LDSP + col8] = *(const uint4*)&Bt[(long)(bcol + row) * K + k0 + col8];
        }
        __syncthreads();
        short8 af[4], bfr[4];
        #pragma unroll
        for (int i = 0; i < 4; ++i)
            af[i] = *(const short8*)&As[(wr * 64 + i * 16 + m0) * LDSP + koff];
        #pragma unroll
        for (int j = 0; j < 4; ++j)
            bfr[j] = *(const short8*)&Bs[(wc * 64 + j * 16 + m0) * LDSP + koff];
        #pragma unroll
        for (int i = 0; i < 4; ++i)
            #pragma unroll
            for (int j = 0; j < 4; ++j)
                acc[i][j] = __builtin_amdgcn_mfma_f32_16x16x32_bf16(af[i], bfr[j], acc[i][j], 0, 0, 0);
        __syncthreads();
    }

    int crow0 = (lane >> 4) * 4;
    int ccol = lane & 15;
    #pragma unroll
    for (int i = 0; i < 4; ++i) {
        #pragma unroll
        for (int r = 0; r < 4; ++r) {
            int grow = brow + wr * 64 + i * 16 + crow0 + r;
            if (grow >= n) continue;
            #pragma unroll
            for (int j = 0; j < 4; ++j) {
                int gcol = bcol + wc * 64 + j * 16 + ccol;
                float v = acc[i][j][r];
                if (bias) v += bias[gcol];
                if (act) v = gelu_f(v);
                if (res) v += res[(long)grow * ldr + gcol];
                if (Cf) Cf[(long)grow * ldc + gcol] = v;
                if (Cb) Cb[(long)grow * ldc + gcol] = f2b(v);
            }
        }
    }
}

// ---------------- LayerNorm rows of 256; input fp32 (af) or bf16 (ab) ----------------
__global__ __launch_bounds__(256) void ln256_kernel(
    const float* __restrict__ af, const ushort* __restrict__ ab,
    const float* __restrict__ res,
    const float* __restrict__ g, const float* __restrict__ bta,
    float* __restrict__ outf, ushort* __restrict__ outb, int n, int post_gelu)
{
    int row = blockIdx.x * 4 + (threadIdx.x >> 6);
    if (row >= n) return;
    int lane = threadIdx.x & 63;
    float4 v;
    if (af) {
        v = *(const float4*)(af + (long)row * H + lane * 4);
    } else {
        ushort4 vb = *(const ushort4*)(ab + (long)row * H + lane * 4);
        v.x = b2f(vb.x); v.y = b2f(vb.y); v.z = b2f(vb.z); v.w = b2f(vb.w);
    }
    if (res) {
        float4 r = *(const float4*)(res + (long)row * H + lane * 4);
        v.x += r.x; v.y += r.y; v.z += r.z; v.w += r.w;
    }
    float s = v.x + v.y + v.z + v.w;
    #pragma unroll
    for (int off = 1; off < 64; off <<= 1) s += __shfl_xor(s, off);
    float mean = s * (1.0f / H);
    float dx = v.x - mean, dy = v.y - mean, dz = v.z - mean, dw = v.w - mean;
    float qs = dx * dx + dy * dy + dz * dz + dw * dw;
    #pragma unroll
    for (int off = 1; off < 64; off <<= 1) qs += __shfl_xor(qs, off);
    float rstd = rsqrtf(qs * (1.0f / H) + 1e-5f);
    float4 gg = *(const float4*)(g + lane * 4);
    float4 bb = *(const float4*)(bta + lane * 4);
    float4 o;
    o.x = dx * rstd * gg.x + bb.x;
    o.y = dy * rstd * gg.y + bb.y;
    o.z = dz * rstd * gg.z + bb.z;
    o.w = dw * rstd * gg.w + bb.w;
    if (post_gelu) { o.x = gelu_f(o.x); o.y = gelu_f(o.y); o.z = gelu_f(o.z); o.w = gelu_f(o.w); }
    if (outf) *(float4*)(outf + (long)row * H + lane * 4) = o;
    if (outb) {
        ushort4 ob = { f2b(o.x), f2b(o.y), f2b(o.z), f2b(o.w) };
        *(ushort4*)(outb + (long)row * H + lane * 4) = ob;
    }
}

// ---------------- conversions ----------------
__global__ __launch_bounds__(256) void xcast_kernel(const float* __restrict__ x,
                                                    ushort* __restrict__ xb)
{
    long i = (long)blockIdx.x * 256 + threadIdx.x;
    if (i >= (long)NN * KIN) return;
    int n = (int)(i / KIN), c = (int)(i % KIN);
    xb[i] = (c < FIN) ? f2b(x[(long)n * FIN + c]) : (ushort)0;
}

__global__ __launch_bounds__(256) void wtin_kernel(const float* __restrict__ W,
                                                   ushort* __restrict__ Wt)
{
    int i = blockIdx.x * 256 + threadIdx.x;
    if (i >= 256 * KIN) return;
    int m = i / KIN, k = i % KIN;
    Wt[i] = (k < FIN) ? f2b(W[(long)k * H + m]) : (ushort)0;
}

__global__ __launch_bounds__(256) void wtqkv_kernel(
    const float* __restrict__ Wq, const float* __restrict__ Wk,
    const float* __restrict__ Wv, ushort* __restrict__ out)
{
    long i = (long)blockIdx.x * 256 + threadIdx.x;
    if (i >= (long)LAYERS * 768 * 256) return;
    int l = (int)(i / (768 * 256));
    int r = (int)(i % (768 * 256));
    int m = r >> 8, k = r & 255;
    const float* W = (m < 256) ? Wq : ((m < 512) ? Wk : Wv);
    out[i] = f2b(W[(long)l * 65536 + (long)k * 256 + (m & 255)]);
}

__global__ __launch_bounds__(256) void wtgen_kernel(
    const float* __restrict__ W, ushort* __restrict__ out, int L, int K, int M)
{
    long i = (long)blockIdx.x * 256 + threadIdx.x;
    if (i >= (long)L * K * M) return;
    int l = (int)(i / ((long)K * M));
    int r = (int)(i % ((long)K * M));
    int m = r / K, k = r % K;
    out[i] = f2b(W[(long)l * K * M + (long)k * M + m]);
}

// ---------------- CSR build ----------------
__global__ __launch_bounds__(256) void deg_kernel(const int* __restrict__ dst,
                                                   int* __restrict__ deg)
{
    int e = blockIdx.x * 256 + threadIdx.x;
    if (e >= NE) return;
    atomicAdd(&deg[dst[e]], 1);
}

__global__ __launch_bounds__(256) void scan1_kernel(const int* __restrict__ deg,
                                                     int* __restrict__ rowptr,
                                                     int* __restrict__ bsum)
{
    __shared__ int buf[256];
    int tid = threadIdx.x;
    int i = blockIdx.x * 256 + tid;
    int v = (i < NN) ? deg[i] : 0;
    buf[tid] = v;
    __syncthreads();
    #pragma unroll
    for (int off = 1; off < 256; off <<= 1) {
        int t = (tid >= off) ? buf[tid - off] : 0;
        __syncthreads();
        buf[tid] += t;
        __syncthreads();
    }
    if (i < NN) rowptr[i] = buf[tid] - v;
    if (tid == 255) bsum[blockIdx.x] = buf[255];
}

__global__ __launch_bounds__(256) void scan2_kernel(int* __restrict__ bsum, int nb)
{
    __shared__ int buf[256];
    int tid = threadIdx.x;
    int v = (tid < nb) ? bsum[tid] : 0;
    buf[tid] = v;
    __syncthreads();
    #pragma unroll
    for (int off = 1; off < 256; off <<= 1) {
        int t = (tid >= off) ? buf[tid - off] : 0;
        __syncthreads();
        buf[tid] += t;
        __syncthreads();
    }
    if (tid < nb) bsum[tid] = buf[tid] - v;
}

__global__ __launch_bounds__(256) void scan3_kernel(int* __restrict__ rowptr,
                                                     const int* __restrict__ bsum)
{
    int i = blockIdx.x * 256 + threadIdx.x;
    if (i < NN) rowptr[i] += bsum[blockIdx.x];
    if (i == 0) rowptr[NN] = NE;
}

__global__ __launch_bounds__(256) void fill_kernel(
    const int* __restrict__ src, const int* __restrict__ dst,
    const float* __restrict__ ea, const int* __restrict__ rowptr,
    int* __restrict__ cursor, int* __restrict__ csr_src,
    float2* __restrict__ csr_ea)
{
    int e = blockIdx.x * 256 + threadIdx.x;
    if (e >= NE) return;
    int d = dst[e];
    int pos = atomicAdd(&cursor[d], 1);
    int j = rowptr[d] + pos;
    csr_src[j] = src[e];
    csr_ea[j] = *(const float2*)(ea + 2 * e);
}

// ---------------- fused gather attention (one wave per node, all 8 heads) ----------------
// qkv: N x 768 bf16 rows = [q(256) | k(256) | v(256)].
// Lane covers 4 channels: c = lane*4 + {0..3}; head = lane>>3 (8 lanes/head).
// Single-stream online softmax with next-edge software prefetch (round-6 form:
// measured better than dual-stream — fewer live VGPRs, no per-edge branch).
__global__ __launch_bounds__(256) void attn_kernel(
    const ushort* __restrict__ qkv,
    const int* __restrict__ rowptr, const int* __restrict__ csr_src,
    const float2* __restrict__ csr_ea,
    const float* __restrict__ We, const float* __restrict__ be,
    ushort* __restrict__ aggb)
{
    int node = blockIdx.x * 4 + (threadIdx.x >> 6);
    if (node >= NN) return;
    int lane = threadIdx.x & 63;
    int h = lane >> 3;                 // global head 0..7
    float w0 = We[h], w1 = We[8 + h], bb = be[h];

    uint2 q2 = *(const uint2*)(qkv + (long)node * 768 + lane * 4);
    int jbeg = rowptr[node], jend = rowptr[node + 1];

    float m = -1e30f, l = 0.f;
    float a0 = 0.f, a1 = 0.f, a2 = 0.f, a3 = 0.f;

    uint2 kN, vN; float2 eaN;
    if (jbeg < jend) {
        int s0 = csr_src[jbeg];
        eaN = csr_ea[jbeg];
        const ushort* kr = qkv + (long)s0 * 768 + 256;
        kN = *(const uint2*)(kr + lane * 4);
        vN = *(const uint2*)(kr + 256 + lane * 4);
    }
    for (int j = jbeg; j < jend; ++j) {
        uint2 k2 = kN, v2 = vN; float2 eab = eaN;
        if (j + 1 < jend) {
            int s1 = csr_src[j + 1];
            eaN = csr_ea[j + 1];
            const ushort* kr = qkv + (long)s1 * 768 + 256;
            kN = *(const uint2*)(kr + lane * 4);
            vN = *(const uint2*)(kr + 256 + lane * 4);
        }
        float p = dot2b(q2.x, k2.x) + dot2b(q2.y, k2.y);
        p += __shfl_xor(p, 1);
        p += __shfl_xor(p, 2);
        p += __shfl_xor(p, 4);         // sum over 8 lanes = 32 channels
        float sc = p * INV_SCALE + eab.x * w0 + eab.y * w1 + bb;
        float vx = __uint_as_float(v2.x << 16);
        float vy = __uint_as_float(v2.x & 0xffff0000u);
        float vz = __uint_as_float(v2.y << 16);
        float vw = __uint_as_float(v2.y & 0xffff0000u);
        float mn = fmaxf(m, sc);
        float scale = __expf(m - mn);
        float e = __expf(sc - mn);
        l = l * scale + e;
        a0 = a0 * scale + e * vx;
        a1 = a1 * scale + e * vy;
        a2 = a2 * scale + e * vz;
        a3 = a3 * scale + e * vw;
        m = mn;
    }
    float inv = 1.0f / (l + 1e-16f);
    ushort4 o = { f2b(a0 * inv), f2b(a1 * inv), f2b(a2 * inv), f2b(a3 * inv) };
    *(ushort4*)(aggb + (long)node * 256 + lane * 4) = o;
}

// ---------------- classifier tail ----------------
__global__ __launch_bounds__(256) void cls_kernel(
    const float* __restrict__ t1, const float* __restrict__ W,
    const float* __restrict__ b, float* __restrict__ out)
{
    int i = blockIdx.x * 256 + threadIdx.x;
    if (i >= NN) return;
    const float* tp = t1 + (long)i * 128;
    float a0 = 0.f, a1 = 0.f;
    #pragma unroll
    for (int j = 0; j < 128; j += 4) {
        float4 t = *(const float4*)(tp + j);
        a0 += t.x * W[(j + 0) * 2] + t.y * W[(j + 1) * 2] + t.z * W[(j + 2) * 2] + t.w * W[(j + 3) * 2];
        a1 += t.x * W[(j + 0) * 2 + 1] + t.y * W[(j + 1) * 2 + 1] + t.z * W[(j + 2) * 2 + 1] + t.w * W[(j + 3) * 2 + 1];
    }
    float l0 = a0 + b[0], l1 = a1 + b[1];
    out[(long)i * 2 + 0] = l0;
    out[(long)i * 2 + 1] = l1;
    float mx = fmaxf(l0, l1);
    float p0 = expf(l0 - mx), p1 = expf(l1 - mx);
    float sden = p0 + p1;
    out[2L * NN + (long)i * 2 + 0] = p0 / sden;
    out[2L * NN + (long)i * 2 + 1] = p1 / sden;
}

extern "C" void kernel_launch(void* const* d_in, const int* in_sizes, int n_in,
                              void* d_out, int out_size, void* d_ws, size_t ws_size,
                              hipStream_t stream) {
    const float* x      = (const float*)d_in[0];
    const int*   ei     = (const int*)d_in[1];
    const float* ea     = (const float*)d_in[2];
    const float* in_W   = (const float*)d_in[3];
    const float* in_b   = (const float*)d_in[4];
    const float* in_g   = (const float*)d_in[5];
    const float* in_bb  = (const float*)d_in[6];
    const float* Wq     = (const float*)d_in[7];
    const float* Wk     = (const float*)d_in[8];
    const float* Wv     = (const float*)d_in[9];
    const float* We     = (const float*)d_in[10];
    const float* be     = (const float*)d_in[11];
    const float* Wo     = (const float*)d_in[12];
    const float* bo     = (const float*)d_in[13];
    const float* ln1_g  = (const float*)d_in[14];
    const float* ln1_b  = (const float*)d_in[15];
    const float* ln2_g  = (const float*)d_in[16];
    const float* ln2_b  = (const float*)d_in[17];
    const float* f1_W   = (const float*)d_in[18];
    const float* f1_b   = (const float*)d_in[19];
    const float* f2_W   = (const float*)d_in[20];
    const float* f2_b   = (const float*)d_in[21];
    const float* cls1_W = (const float*)d_in[22];
    const float* cls1_b = (const float*)d_in[23];
    const float* cls2_W = (const float*)d_in[24];
    const float* cls2_b = (const float*)d_in[25];
    float* out = (float*)d_out;

    const int* src = ei;
    const int* dst = ei + NE;

    // ---- workspace layout (~197 MB) ----
    char* w = (char*)d_ws;
    float* B0 = (float*)w;            w += (size_t)NN * H * 4;       // h / out (fp32)
    ushort* hb = (ushort*)w;          w += (size_t)NN * H * 2;       // bf16 activations
    char* pool = w;                   w += (size_t)NN * 1024 * 2;    // 102.4 MB union
    ushort* qkv  = (ushort*)pool;                                    // N x 768 bf16
    ushort* aggb = (ushort*)(pool + (size_t)NN * 768 * 2);           // N x 256 bf16
    float*  tproj = (float*)pool;                                    // input-proj t
    ushort* xb   = (ushort*)(pool + (size_t)NN * H * 4);             // N x 224 bf16
    ushort* tb   = (ushort*)pool;                                    // FFN N x 1024 bf16
    float*  t1   = (float*)pool;                                     // cls hidden fp32
    int* deg    = (int*)w;            w += (size_t)NN * 4;
    int* cursor = (int*)w;            w += (size_t)NN * 4;
    int* rowptr = (int*)w;            w += (size_t)(NN + 2) * 4;
    int* bsum   = (int*)w;            w += 1024;
    int* csr_src = (int*)w;           w += (size_t)NE * 4;
    float2* csr_ea = (float2*)w;      w += (size_t)NE * 8;
    ushort* wqkv_t = (ushort*)w;      w += (size_t)LAYERS * 768 * 256 * 2;
    ushort* wo_t  = (ushort*)w;       w += (size_t)LAYERS * 65536 * 2;
    ushort* f1_t  = (ushort*)w;       w += (size_t)LAYERS * 262144 * 2;
    ushort* f2_t  = (ushort*)w;       w += (size_t)LAYERS * 262144 * 2;
    ushort* c1_t  = (ushort*)w;       w += (size_t)32768 * 2;
    ushort* inw_t = (ushort*)w;       w += (size_t)256 * KIN * 2;

    dim3 blk(256);
    const int ln_grid = (NN + 3) / 4;
    const int e_grid = (NE + 255) / 256;
    const int n_grid = (NN + 255) / 256;
    const int ty = (NN + 127) / 128;

    // ---- CSR build ----
    hipMemsetAsync(deg, 0, (size_t)NN * 4, stream);
    hipMemsetAsync(cursor, 0, (size_t)NN * 4, stream);
    deg_kernel<<<e_grid, blk, 0, stream>>>(dst, deg);
    scan1_kernel<<<n_grid, blk, 0, stream>>>(deg, rowptr, bsum);
    scan2_kernel<<<1, blk, 0, stream>>>(bsum, n_grid);
    scan3_kernel<<<n_grid, blk, 0, stream>>>(rowptr, bsum);
    fill_kernel<<<e_grid, blk, 0, stream>>>(src, dst, ea, rowptr, cursor, csr_src, csr_ea);

    // ---- weight convert/transpose ----
    wtqkv_kernel<<<(int)(((long)LAYERS * 768 * 256 + 255) / 256), blk, 0, stream>>>(Wq, Wk, Wv, wqkv_t);
    wtgen_kernel<<<(int)(((long)LAYERS * 65536 + 255) / 256), blk, 0, stream>>>(Wo, wo_t, LAYERS, 256, 256);
    wtgen_kernel<<<(int)(((long)LAYERS * 262144 + 255) / 256), blk, 0, stream>>>(f1_W, f1_t, LAYERS, 256, 1024);
    wtgen_kernel<<<(int)(((long)LAYERS * 262144 + 255) / 256), blk, 0, stream>>>(f2_W, f2_t, LAYERS, 1024, 256);
    wtgen_kernel<<<(32768 + 255) / 256, blk, 0, stream>>>(cls1_W, c1_t, 1, 256, 128);
    wtin_kernel<<<(256 * KIN + 255) / 256, blk, 0, stream>>>(in_W, inw_t);

    // ---- input projection (MFMA) ----
    xcast_kernel<<<(int)(((long)NN * KIN + 255) / 256), blk, 0, stream>>>(x, xb);
    {
        dim3 g(2, ty);
        gemm_bf16_kernel<<<g, blk, 0, stream>>>(xb, KIN, inw_t, in_b, nullptr, 0,
                                                tproj, nullptr, H, NN, KIN, 0);
        ln256_kernel<<<ln_grid, blk, 0, stream>>>(tproj, nullptr, nullptr, in_g, in_bb, B0, nullptr, NN, 1);
    }

    for (int l = 0; l < LAYERS; ++l) {
        const float* we  = We + (long)l * 16;
        const float* bel = be + (long)l * 8;
        const float* bol = bo + (long)l * H;
        const float* g1 = ln1_g + (long)l * H;
        const float* b1 = ln1_b + (long)l * H;
        const float* g2 = ln2_g + (long)l * H;
        const float* b2 = ln2_b + (long)l * H;
        const float* bf1 = f1_b + (long)l * FF;
        const float* bf2 = f2_b + (long)l * H;

        // hb = bf16(LN1(h))
        ln256_kernel<<<ln_grid, blk, 0, stream>>>(B0, nullptr, nullptr, g1, b1, nullptr, hb, NN, 0);

        // fused QKV (M=768) + 8-head gather attention
        dim3 gq(6, ty);
        gemm_bf16_kernel<<<gq, blk, 0, stream>>>(hb, H, wqkv_t + (long)l * 768 * 256,
            nullptr, nullptr, 0, nullptr, qkv, 768, NN, H, 0);
        attn_kernel<<<(NN + 3) / 4, blk, 0, stream>>>(qkv, rowptr, csr_src, csr_ea, we, bel, aggb);

        // B0 = LN(aggb@Wo^T + bo + h); hb = bf16(out)
        dim3 gh(2, ty);
        gemm_bf16_kernel<<<gh, blk, 0, stream>>>(aggb, H, wo_t + (long)l * 65536,
            bol, nullptr, 0, nullptr, qkv, H, NN, H, 0);   // reuse qkv head as woo
        ln256_kernel<<<ln_grid, blk, 0, stream>>>(nullptr, qkv, B0, g2, b2, B0, hb, NN, 0);

        // FFN one-shot: tb = gelu(hb@f1^T+b) bf16 ; B0 = tb@f2^T + b + B0
        dim3 gf(8, ty);
        gemm_bf16_kernel<<<gf, blk, 0, stream>>>(hb, H, f1_t + (long)l * 262144,
            bf1, nullptr, 0, nullptr, tb, FF, NN, H, 1);
        dim3 gb(2, ty);
        gemm_bf16_kernel<<<gb, blk, 0, stream>>>(tb, FF, f2_t + (long)l * 262144,
            bf2, B0, H, B0, (l == LAYERS - 1) ? hb : nullptr, H, NN, FF, 0);
    }

    // ---- classifier ----
    {
        dim3 g(1, ty);
        gemm_bf16_kernel<<<g, blk, 0, stream>>>(hb, H, c1_t, cls1_b, nullptr, 0, t1, nullptr, 128, NN, H, 1);
        cls_kernel<<<n_grid, blk, 0, stream>>>(t1, cls2_W, cls2_b, out);
    }
}